// Round 4
// baseline (476.862 us; speedup 1.0000x reference)
//
#include <hip/hip_runtime.h>
#include <hip/hip_bf16.h>
#include <hip/hip_fp16.h>
#include <float.h>
#include <stdint.h>

#define N_CAT   100000
#define N_USERS 50000
#define N_REL   32
#define D       64
#define NEDGE   1600000
#define NNZ     1000000

#define EB_SHIFT 9
#define EB_SIZE  512
#define NBKE     ((N_CAT + EB_SIZE - 1) / EB_SIZE)    // 196 edge buckets
#define UB_SHIFT 8
#define UB_SIZE  256
#define NBKU     ((N_USERS + UB_SIZE - 1) / UB_SIZE)  // 196 user buckets
#define NBK      (NBKE + NBKU)                        // 392

#define T1   4096      // pass1 tile (16 recs/thread @ 256 threads)
#define ECAP 15360     // pass2 edge bucket LDS capacity
#define UCAP 7680      // pass2 user bucket LDS capacity

// ---------------------------------------------------------------------------
// ws: norm2[N_CAT*32] f32 | ccnt[392] | cbase_e[197] | cbase_u[197] |
//     ccur_e[196] | ccur_u[196] | offs_e[100001] | offs_u[50001] |
//     sorted_ta[NEDGE] int | sorted_cv[NNZ] int2 | cat_f16[N_CAT*64] (aligned)
// ---------------------------------------------------------------------------

__device__ __forceinline__ unsigned int pack_half2(float a, float b) {
    return (unsigned int)__half_as_ushort(__float2half_rn(a)) |
           ((unsigned int)__half_as_ushort(__float2half_rn(b)) << 16);
}

// Gather one 64-dim row, 8 lanes x 8 dims. F16: one uint4 = one 128B line.
template<int F16>
__device__ __forceinline__ void load_row8(const float4* __restrict__ catv4,
                                          const uint4* __restrict__ cath4,
                                          int row, int gl, float f[8]) {
    if (F16) {
        uint4 h = cath4[(size_t)row * 8 + gl];
        const __half2* hp = (const __half2*)&h;
        float2 a = __half22float2(hp[0]);
        float2 b = __half22float2(hp[1]);
        float2 c = __half22float2(hp[2]);
        float2 d = __half22float2(hp[3]);
        f[0] = a.x; f[1] = a.y; f[2] = b.x; f[3] = b.y;
        f[4] = c.x; f[5] = c.y; f[6] = d.x; f[7] = d.y;
    } else {
        float4 a = catv4[(size_t)row * 16 + gl * 2];
        float4 b = catv4[(size_t)row * 16 + gl * 2 + 1];
        f[0] = a.x; f[1] = a.y; f[2] = a.z; f[3] = a.w;
        f[4] = b.x; f[5] = b.y; f[6] = b.z; f[7] = b.w;
    }
}

// Butterfly reduce-scatter over the 8 groups: input a[8] (k-indexed partials
// of dims (lane&7)*8+k, partial over group lane>>3). Output: full sum of dim
// (lane&7)*8 + ((b3<<2)|(b4<<1)|b5) at this lane. 7 shfl vs 24 for all-reduce;
// identical addition tree -> bitwise-identical to the old xor8/16/32 reduce.
__device__ __forceinline__ float reduce_scatter8(const float a[8], int lane) {
    int b3 = (lane >> 3) & 1, b4 = (lane >> 4) & 1, b5 = (lane >> 5) & 1;
    float r[4];
#pragma unroll
    for (int j = 0; j < 4; ++j) {
        float x = b3 ? a[j] : a[j + 4];       // send: what partner keeps
        float k = b3 ? a[j + 4] : a[j];       // keep
        r[j] = k + __shfl_xor(x, 8);
    }
    float s[2];
#pragma unroll
    for (int j = 0; j < 2; ++j) {
        float x = b4 ? r[j] : r[j + 2];
        float k = b4 ? r[j + 2] : r[j];
        s[j] = k + __shfl_xor(x, 16);
    }
    float x = b5 ? s[0] : s[1];
    float k = b5 ? s[1] : s[0];
    return k + __shfl_xor(x, 32);
}

__device__ __forceinline__ int dim_of_lane(int lane) {
    int g = lane >> 3;
    return ((lane & 7) << 3) | ((g & 1) << 2) | (g & 2) | (g >> 2);
}

// norm2[n][r] = sum_d cat[n][d]^2 * W[r][d]^2.
template<int W16>
__global__ __launch_bounds__(256) void norm2_kernel(
        const float* __restrict__ cat,
        const float* __restrict__ W,
        float* __restrict__ norm2,
        unsigned short* __restrict__ cath) {
    __shared__ float4 w2[N_REL * 16];   // squared W, 8 KB
    int t = threadIdx.x;
    const float4* Wv = (const float4*)W;
    for (int i = t; i < N_REL * 16; i += 256) {
        float4 v = Wv[i];
        v.x *= v.x; v.y *= v.y; v.z *= v.z; v.w *= v.w;
        w2[i] = v;
    }
    __syncthreads();

    int node = blockIdx.x * 64 + (t >> 2);
    int q    = t & 3;
    if (node >= N_CAT) return;

    const float4* catv = (const float4*)cat;
    float acc[N_REL];
#pragma unroll
    for (int r = 0; r < N_REL; ++r) acc[r] = 0.f;

    uint2 hp[4];
#pragma unroll
    for (int c = 0; c < 4; ++c) {
        float4 xv = catv[(size_t)node * 16 + q * 4 + c];
        if (W16) {
            hp[c].x = pack_half2(xv.x, xv.y);
            hp[c].y = pack_half2(xv.z, xv.w);
        }
        xv.x *= xv.x; xv.y *= xv.y; xv.z *= xv.z; xv.w *= xv.w;
#pragma unroll
        for (int r = 0; r < N_REL; ++r) {
            float4 wv = w2[r * 16 + q * 4 + c];
            acc[r] += xv.x * wv.x + xv.y * wv.y + xv.z * wv.z + xv.w * wv.w;
        }
    }
    if (W16) {
        uint4* cv16 = (uint4*)cath;
        cv16[(size_t)node * 8 + q * 2]     = make_uint4(hp[0].x, hp[0].y, hp[1].x, hp[1].y);
        cv16[(size_t)node * 8 + q * 2 + 1] = make_uint4(hp[2].x, hp[2].y, hp[3].x, hp[3].y);
    }
#pragma unroll
    for (int r = 0; r < N_REL; ++r) {
        acc[r] += __shfl_xor(acc[r], 1);
        acc[r] += __shfl_xor(acc[r], 2);
    }
    float4* nv = (float4*)norm2;
    size_t base = (size_t)node * 8 + q * 2;
    if (q == 0) {
        nv[base]     = make_float4(acc[0],  acc[1],  acc[2],  acc[3]);
        nv[base + 1] = make_float4(acc[4],  acc[5],  acc[6],  acc[7]);
    } else if (q == 1) {
        nv[base]     = make_float4(acc[8],  acc[9],  acc[10], acc[11]);
        nv[base + 1] = make_float4(acc[12], acc[13], acc[14], acc[15]);
    } else if (q == 2) {
        nv[base]     = make_float4(acc[16], acc[17], acc[18], acc[19]);
        nv[base + 1] = make_float4(acc[20], acc[21], acc[22], acc[23]);
    } else {
        nv[base]     = make_float4(acc[24], acc[25], acc[26], acc[27]);
        nv[base + 1] = make_float4(acc[28], acc[29], acc[30], acc[31]);
    }
}

// per-WG LDS histogram over 392 coarse buckets, single flush
__global__ void coarse_hist_kernel(const int* __restrict__ head,
                                   const int* __restrict__ imr,
                                   int* __restrict__ ccnt) {
    __shared__ int h[NBK];
    int t = threadIdx.x;
    for (int i = t; i < NBK; i += 256) h[i] = 0;
    __syncthreads();
    int stride = gridDim.x * 256;
    for (int i = blockIdx.x * 256 + t; i < NEDGE + NNZ; i += stride) {
        if (i < NEDGE) atomicAdd(&h[head[i] >> EB_SHIFT], 1);
        else           atomicAdd(&h[NBKE + (imr[i - NEDGE] >> UB_SHIFT)], 1);
    }
    __syncthreads();
    for (int i = t; i < NBK; i += 256) if (h[i]) atomicAdd(&ccnt[i], h[i]);
}

// single-WG scan of 392 coarse bins -> bucket bases + cursors + sentinels
__global__ void coarse_scan_kernel(const int* __restrict__ ccnt,
                                   int* __restrict__ cbase_e, int* __restrict__ cbase_u,
                                   int* __restrict__ ccur_e,  int* __restrict__ ccur_u,
                                   int* __restrict__ offs_e,  int* __restrict__ offs_u) {
    __shared__ int sc[256];
    int t = threadIdx.x;
    int c = (t < NBKE) ? ccnt[t] : 0;
    sc[t] = c; __syncthreads();
    for (int off = 1; off < 256; off <<= 1) {
        int v = (t >= off) ? sc[t - off] : 0; __syncthreads();
        sc[t] += v; __syncthreads();
    }
    int excl = sc[t] - c;
    if (t < NBKE) { cbase_e[t] = excl; ccur_e[t] = excl; }
    if (t == NBKE - 1) cbase_e[NBKE] = excl + c;
    __syncthreads();
    c = (t < NBKU) ? ccnt[NBKE + t] : 0;
    sc[t] = c; __syncthreads();
    for (int off = 1; off < 256; off <<= 1) {
        int v = (t >= off) ? sc[t - off] : 0; __syncthreads();
        sc[t] += v; __syncthreads();
    }
    excl = sc[t] - c;
    if (t < NBKU) { cbase_u[t] = excl; ccur_u[t] = excl; }
    if (t == NBKU - 1) cbase_u[NBKU] = excl + c;
    if (t == 0) { offs_e[N_CAT] = NEDGE; offs_u[N_USERS] = NNZ; }
}

// pass1 edges: tile -> LDS count/scan -> ONE global atomic per (tile,bucket)
__global__ __launch_bounds__(256) void pass1_edges_kernel(
        const int* __restrict__ head, const int* __restrict__ tail,
        const int* __restrict__ etype, int* __restrict__ ccur_e,
        int* __restrict__ sorted_ta) {
    __shared__ int cnt[256], loc[256], base[256], sc[256];
    __shared__ int stage[T1];
    __shared__ int gpos[T1];
    int t = threadIdx.x;
    int tile = blockIdx.x * T1;
    cnt[t] = 0;
    __syncthreads();
    int rec[16], bk[16];
#pragma unroll
    for (int k = 0; k < 16; ++k) {
        int i = tile + k * 256 + t;
        if (i < NEDGE) {
            int h = head[i], tl = tail[i], r = etype[i] - 1;
            bk[k]  = h >> EB_SHIFT;
            rec[k] = ((h & (EB_SIZE - 1)) << 22) | (tl << 5) | r;
            atomicAdd(&cnt[bk[k]], 1);
        } else bk[k] = -1;
    }
    __syncthreads();
    int c = cnt[t];
    sc[t] = c; __syncthreads();
    for (int off = 1; off < 256; off <<= 1) {
        int v = (t >= off) ? sc[t - off] : 0; __syncthreads();
        sc[t] += v; __syncthreads();
    }
    loc[t] = sc[t] - c;
    if (t < NBKE && c > 0) base[t] = atomicAdd(&ccur_e[t], c);
    __syncthreads();
    cnt[t] = loc[t];
    __syncthreads();
#pragma unroll
    for (int k = 0; k < 16; ++k) {
        if (bk[k] >= 0) {
            int p = atomicAdd(&cnt[bk[k]], 1);
            stage[p] = rec[k];
            gpos[p]  = base[bk[k]] + (p - loc[bk[k]]);
        }
    }
    __syncthreads();
    int nv = min(T1, NEDGE - tile);
    for (int i = t; i < nv; i += 256) sorted_ta[gpos[i]] = stage[i];
}

__global__ __launch_bounds__(256) void pass1_users_kernel(
        const int* __restrict__ imr, const int* __restrict__ imc,
        const float* __restrict__ imv, int* __restrict__ ccur_u,
        int2* __restrict__ sorted_cv) {
    __shared__ int cnt[256], loc[256], base[256], sc[256];
    __shared__ int2 stage[T1];
    __shared__ int gpos[T1];
    int t = threadIdx.x;
    int tile = blockIdx.x * T1;
    cnt[t] = 0;
    __syncthreads();
    int2 rec[16]; int bk[16];
#pragma unroll
    for (int k = 0; k < 16; ++k) {
        int i = tile + k * 256 + t;
        if (i < NNZ) {
            int rr = imr[i];
            bk[k]  = rr >> UB_SHIFT;
            rec[k] = make_int2(((rr & (UB_SIZE - 1)) << 17) | imc[i],
                               __float_as_int(imv[i]));
            atomicAdd(&cnt[bk[k]], 1);
        } else bk[k] = -1;
    }
    __syncthreads();
    int c = cnt[t];
    sc[t] = c; __syncthreads();
    for (int off = 1; off < 256; off <<= 1) {
        int v = (t >= off) ? sc[t - off] : 0; __syncthreads();
        sc[t] += v; __syncthreads();
    }
    loc[t] = sc[t] - c;
    if (t < NBKU && c > 0) base[t] = atomicAdd(&ccur_u[t], c);
    __syncthreads();
    cnt[t] = loc[t];
    __syncthreads();
#pragma unroll
    for (int k = 0; k < 16; ++k) {
        if (bk[k] >= 0) {
            int p = atomicAdd(&cnt[bk[k]], 1);
            stage[p] = rec[k];
            gpos[p]  = base[bk[k]] + (p - loc[bk[k]]);
        }
    }
    __syncthreads();
    int nv = min(T1, NNZ - tile);
    for (int i = t; i < nv; i += 256) sorted_cv[gpos[i]] = stage[i];
}

// pass2: one WG per coarse bucket; fine counting-sort in LDS; writes fine offs
__global__ __launch_bounds__(256) void pass2_kernel(
        const int* __restrict__ cbase_e, const int* __restrict__ cbase_u,
        int* __restrict__ offs_e, int* __restrict__ offs_u,
        int* __restrict__ sorted_ta, int2* __restrict__ sorted_cv) {
    __shared__ int lds[UCAP * 2];        // 60 KB
    __shared__ int fh[EB_SIZE + 1];
    __shared__ int sc[256];
    int t = threadIdx.x;
    int b = blockIdx.x;
    if (b < NBKE) {
        int h0 = b << EB_SHIFT;
        int start = cbase_e[b], end = cbase_e[b + 1];
        int n = min(end - start, ECAP);
        for (int i = t; i < n; i += 256) lds[i] = sorted_ta[start + i];
        fh[2 * t] = 0; fh[2 * t + 1] = 0;
        __syncthreads();
        for (int i = t; i < n; i += 256) atomicAdd(&fh[lds[i] >> 22], 1);
        __syncthreads();
        int a = fh[2 * t], b2 = fh[2 * t + 1];
        sc[t] = a + b2; __syncthreads();
        for (int off = 1; off < 256; off <<= 1) {
            int v = (t >= off) ? sc[t - off] : 0; __syncthreads();
            sc[t] += v; __syncthreads();
        }
        int pe = sc[t] - (a + b2);
        int lim = min(EB_SIZE, N_CAT - h0);
        if (2 * t     < lim) offs_e[h0 + 2 * t]     = start + pe;
        if (2 * t + 1 < lim) offs_e[h0 + 2 * t + 1] = start + pe + a;
        fh[2 * t] = pe; fh[2 * t + 1] = pe + a;
        __syncthreads();
        for (int i = t; i < n; i += 256) {
            int rec = lds[i];
            int p = atomicAdd(&fh[rec >> 22], 1);
            sorted_ta[start + p] = rec & 0x3FFFFF;     // (tail<<5)|rel
        }
    } else {
        int k = b - NBKE;
        int u0 = k << UB_SHIFT;
        int start = cbase_u[k], end = cbase_u[k + 1];
        int n = min(end - start, UCAP);
        int2* lds2 = (int2*)lds;
        for (int i = t; i < n; i += 256) lds2[i] = sorted_cv[start + i];
        fh[t] = 0;
        __syncthreads();
        for (int i = t; i < n; i += 256) atomicAdd(&fh[lds2[i].x >> 17], 1);
        __syncthreads();
        int c = fh[t];
        sc[t] = c; __syncthreads();
        for (int off = 1; off < 256; off <<= 1) {
            int v = (t >= off) ? sc[t - off] : 0; __syncthreads();
            sc[t] += v; __syncthreads();
        }
        int excl = sc[t] - c;
        int lim = min(UB_SIZE, N_USERS - u0);
        if (t < lim) offs_u[u0 + t] = start + excl;
        fh[t] = excl;
        __syncthreads();
        for (int i = t; i < n; i += 256) {
            int2 rec = lds2[i];
            int p = atomicAdd(&fh[rec.x >> 17], 1);
            sorted_cv[start + p] = make_int2(rec.x & 0x1FFFF, rec.y);
        }
    }
}

#define FMA8(ACC, WS, F, W0, W1)                                         \
    ACC[0] += WS * F[0] * W0.x;  ACC[1] += WS * F[1] * W0.y;             \
    ACC[2] += WS * F[2] * W0.z;  ACC[3] += WS * F[3] * W0.w;             \
    ACC[4] += WS * F[4] * W1.x;  ACC[5] += WS * F[5] * W1.y;             \
    ACC[6] += WS * F[6] * W1.z;  ACC[7] += WS * F[7] * W1.w;

// W row segment from GLOBAL (L1-hot, 8 KB table): offloads the saturated DS
// pipe; per-instr gathers up to 8 distinct 128B W-lines, all L1-resident.
__device__ __forceinline__ void wrow(const float* __restrict__ W, int r, int gl,
                                     float4& w0, float4& w1) {
    const float4* p = (const float4*)(W + (size_t)r * D) + gl * 2;
    w0 = p[0]; w1 = p[1];
}

// one wave per head; no LDS, no barriers. DS pipe use per wave: ~8 broadcast
// shfl + ~10 softmax shfl + 7 reduce-scatter shfl (was ~50 with LDS W +
// 24-shfl all-reduce). W reads + norm2 reads ride the VMEM pipe (L1-hot).
template<int F16>
__global__ __launch_bounds__(256, 4) void cat_agg_sorted_kernel(
        const int* __restrict__ offs_e,
        const int* __restrict__ sorted_ta,
        const float* __restrict__ norm2,
        const float* __restrict__ cat,
        const uint4* __restrict__ cath4,
        const float* __restrict__ W,
        float* __restrict__ cat_agg) {
    const float4* catv4 = (const float4*)cat;
    int wv   = threadIdx.x >> 6;
    int lane = threadIdx.x & 63;
    int grp  = lane >> 3;
    int gl   = lane & 7;
    int h = blockIdx.x * 4 + wv;
    int start = offs_e[h];
    int end   = offs_e[h + 1];
    int deg   = end - start;

    float accA[8], accB[8];
#pragma unroll
    for (int k = 0; k < 8; ++k) { accA[k] = 0.f; accB[k] = 0.f; }

    if (deg <= 32) {
        int rec = 0;
        if (lane < deg) rec = sorted_ta[start + lane];
        int tt = rec >> 5, r = rec & 31;
        float n2t = norm2[(size_t)tt * N_REL + r];
        float n2h = norm2[(size_t)h  * N_REL + r];

        // prefetch row data for both FMA blocks NOW (overlaps softmax chain)
        int tA0 = __shfl(rec, grp),      tB0 = __shfl(rec, 8 + grp);
        float fA0[8], fB0[8], fA1[8], fB1[8];
        load_row8<F16>(catv4, cath4, tA0 >> 5, gl, fA0);
        load_row8<F16>(catv4, cath4, tB0 >> 5, gl, fB0);
        int tA1 = 0, tB1 = 0;
        if (deg > 16) {
            tA1 = __shfl(rec, 16 + grp); tB1 = __shfl(rec, 24 + grp);
            load_row8<F16>(catv4, cath4, tA1 >> 5, gl, fA1);
            load_row8<F16>(catv4, cath4, tB1 >> 5, gl, fB1);
        }

        float att = (lane < deg) ? n2h * n2t : -FLT_MAX;
        float m = att;
        m = fmaxf(m, __shfl_xor(m, 1));
        m = fmaxf(m, __shfl_xor(m, 2));
        m = fmaxf(m, __shfl_xor(m, 4));
        m = fmaxf(m, __shfl_xor(m, 8));
        if (deg > 16) m = fmaxf(m, __shfl_xor(m, 16));
        float ex = (lane < deg) ? __expf(att - m) : 0.f;
        float ssum = ex;
        ssum += __shfl_xor(ssum, 1);
        ssum += __shfl_xor(ssum, 2);
        ssum += __shfl_xor(ssum, 4);
        ssum += __shfl_xor(ssum, 8);
        if (deg > 16) ssum += __shfl_xor(ssum, 16);
        float w = (deg > 0) ? ex / ssum : 0.f;

        float wA0 = __shfl(w, grp), wB0 = __shfl(w, 8 + grp);
        float4 wa00, wa01, wb00, wb01;
        wrow(W, tA0 & 31, gl, wa00, wa01);
        wrow(W, tB0 & 31, gl, wb00, wb01);
        FMA8(accA, wA0, fA0, wa00, wa01)
        FMA8(accB, wB0, fB0, wb00, wb01)
        if (deg > 16) {
            float wA1 = __shfl(w, 16 + grp), wB1 = __shfl(w, 24 + grp);
            float4 wa10, wa11, wb10, wb11;
            wrow(W, tA1 & 31, gl, wa10, wa11);
            wrow(W, tB1 & 31, gl, wb10, wb11);
            FMA8(accA, wA1, fA1, wa10, wa11)
            FMA8(accB, wB1, fB1, wb10, wb11)
        }
    } else if (deg <= 64) {
        int   rec = 0;
        float att = -FLT_MAX;
        if (lane < deg) {
            rec = sorted_ta[start + lane];
            int tt = rec >> 5, r = rec & 31;
            att = norm2[h * N_REL + r] * norm2[(size_t)tt * N_REL + r];
        }
        float m = att;
#pragma unroll
        for (int off = 32; off > 0; off >>= 1) m = fmaxf(m, __shfl_xor(m, off));
        float ex = (lane < deg) ? __expf(att - m) : 0.f;
        float ssum = ex;
#pragma unroll
        for (int off = 32; off > 0; off >>= 1) ssum += __shfl_xor(ssum, off);
        float w = (deg > 0) ? ex / ssum : 0.f;

        for (int e = 0; e < deg; e += 16) {
            int   tA = __shfl(rec, e + grp);
            float wA = __shfl(w,   e + grp);
            int   tB = __shfl(rec, e + 8 + grp);
            float wB = __shfl(w,   e + 8 + grp);
            float fA[8], fB[8];
            load_row8<F16>(catv4, cath4, tA >> 5, gl, fA);
            load_row8<F16>(catv4, cath4, tB >> 5, gl, fB);
            float4 wa0, wa1, wb0, wb1;
            wrow(W, tA & 31, gl, wa0, wa1);
            wrow(W, tB & 31, gl, wb0, wb1);
            FMA8(accA, wA, fA, wa0, wa1)
            FMA8(accB, wB, fB, wb0, wb1)
        }
    } else {
        float m = -FLT_MAX;
        for (int j = lane; j < deg; j += 64) {
            int rec = sorted_ta[start + j];
            int tt = rec >> 5, r = rec & 31;
            m = fmaxf(m, norm2[h * N_REL + r] * norm2[(size_t)tt * N_REL + r]);
        }
#pragma unroll
        for (int off = 32; off > 0; off >>= 1) m = fmaxf(m, __shfl_xor(m, off));
        float ssum = 0.f;
        for (int j = lane; j < deg; j += 64) {
            int rec = sorted_ta[start + j];
            int tt = rec >> 5, r = rec & 31;
            ssum += __expf(norm2[h * N_REL + r] * norm2[(size_t)tt * N_REL + r] - m);
        }
#pragma unroll
        for (int off = 32; off > 0; off >>= 1) ssum += __shfl_xor(ssum, off);
        float inv = 1.f / ssum;
        for (int j0 = 0; j0 < deg; j0 += 64) {
            int n = min(64, deg - j0);
            int   rec = 0;
            float w   = 0.f;
            if (lane < n) {
                rec = sorted_ta[start + j0 + lane];
                int tt = rec >> 5, r = rec & 31;
                w = __expf(norm2[h * N_REL + r] * norm2[(size_t)tt * N_REL + r] - m) * inv;
            }
            for (int e = 0; e < n; e += 16) {
                int   tA = __shfl(rec, e + grp);
                float wA = __shfl(w,   e + grp);
                int   tB = __shfl(rec, e + 8 + grp);
                float wB = __shfl(w,   e + 8 + grp);
                float fA[8], fB[8];
                load_row8<F16>(catv4, cath4, tA >> 5, gl, fA);
                load_row8<F16>(catv4, cath4, tB >> 5, gl, fB);
                float4 wa0, wa1, wb0, wb1;
                wrow(W, tA & 31, gl, wa0, wa1);
                wrow(W, tB & 31, gl, wb0, wb1);
                FMA8(accA, wA, fA, wa0, wa1)
                FMA8(accB, wB, fB, wb0, wb1)
            }
        }
    }

    float a[8];
#pragma unroll
    for (int k = 0; k < 8; ++k) a[k] = accA[k] + accB[k];
    float tot = reduce_scatter8(a, lane);
    cat_agg[(size_t)h * D + dim_of_lane(lane)] = tot;
}

// spmm: gather structure unchanged; epilogue runs on registers + VMEM.
// wreg[r] = W[r][dim] per lane (loaded before the gather, L1/L2-hot).
// Only LDS use: 32-float score exchange (wave-private, no barriers).
template<int F16>
__global__ __launch_bounds__(256, 4) void spmm_user_kernel(
        const int* __restrict__ offs_u,
        const int2* __restrict__ sorted_cv,
        const float* __restrict__ cat,
        const uint4* __restrict__ cath4,
        const float* __restrict__ uemb,
        const float* __restrict__ W,
        float* __restrict__ uagg) {
    __shared__ float s_score[4][N_REL];
    const float4* catv4 = (const float4*)cat;
    int wv   = threadIdx.x >> 6;
    int lane = threadIdx.x & 63;
    int grp  = lane >> 3;
    int gl   = lane & 7;
    int dim  = dim_of_lane(lane);
    int u = blockIdx.x * 4 + wv;
    int start = offs_u[u];
    int end   = offs_u[u + 1];
    int deg   = end - start;

    // per-lane W column at this lane's output dim (issued early; L1/L2-hot)
    float wreg[N_REL];
#pragma unroll
    for (int r = 0; r < N_REL; ++r) wreg[r] = W[(size_t)r * D + dim];

    float accA[8], accB[8];
#pragma unroll
    for (int k = 0; k < 8; ++k) { accA[k] = 0.f; accB[k] = 0.f; }

    if (deg <= 32) {
        int my_c = 0; float my_v = 0.f;
        if (lane < deg) {
            int2 cv = sorted_cv[start + lane];
            my_c = cv.x;
            my_v = __int_as_float(cv.y);
        }
        int   cA0 = __shfl(my_c, grp),     cB0 = __shfl(my_c, 8 + grp);
        float vA0 = __shfl(my_v, grp),     vB0 = __shfl(my_v, 8 + grp);
        float fA0[8], fB0[8], fA1[8], fB1[8];
        load_row8<F16>(catv4, cath4, cA0, gl, fA0);
        load_row8<F16>(catv4, cath4, cB0, gl, fB0);
        float vA1 = 0.f, vB1 = 0.f;
        if (deg > 16) {
            int cA1 = __shfl(my_c, 16 + grp), cB1 = __shfl(my_c, 24 + grp);
            vA1 = __shfl(my_v, 16 + grp); vB1 = __shfl(my_v, 24 + grp);
            load_row8<F16>(catv4, cath4, cA1, gl, fA1);
            load_row8<F16>(catv4, cath4, cB1, gl, fB1);
#pragma unroll
            for (int k = 0; k < 8; ++k) {
                accA[k] += vA1 * fA1[k];
                accB[k] += vB1 * fB1[k];
            }
        }
#pragma unroll
        for (int k = 0; k < 8; ++k) {
            accA[k] += vA0 * fA0[k];
            accB[k] += vB0 * fB0[k];
        }
    } else {
        for (int j0 = 0; j0 < deg; j0 += 64) {
            int n = min(64, deg - j0);
            int   my_c = 0;
            float my_v = 0.f;
            if (lane < n) {
                int2 cv = sorted_cv[start + j0 + lane];
                my_c = cv.x;
                my_v = __int_as_float(cv.y);
            }
            for (int e = 0; e < n; e += 16) {
                int   cA = __shfl(my_c, e + grp);
                float vA = __shfl(my_v, e + grp);
                int   cB = __shfl(my_c, e + 8 + grp);
                float vB = __shfl(my_v, e + 8 + grp);
                float fA[8], fB[8];
                load_row8<F16>(catv4, cath4, cA, gl, fA);
                load_row8<F16>(catv4, cath4, cB, gl, fB);
#pragma unroll
                for (int k = 0; k < 8; ++k) {
                    accA[k] += vA * fA[k];
                    accB[k] += vB * fB[k];
                }
            }
        }
    }

    float a[8];
#pragma unroll
    for (int k = 0; k < 8; ++k) a[k] = accA[k] + accB[k];
    float tot = reduce_scatter8(a, lane);

    // score dot: rel = lane&31; both half-waves compute identical values.
    // u row + W row read via VMEM broadcast (L1-hot), off the DS pipe.
    int rel = lane & 31;
    float dot = 0.f;
    {
        const float4* Wr = (const float4*)(W + (size_t)rel * D);
        const float4* ur = (const float4*)(uemb + (size_t)u * D);
#pragma unroll
        for (int i = 0; i < 16; ++i) {
            float4 wv4 = Wr[i], uv4 = ur[i];
            dot += wv4.x * uv4.x + wv4.y * uv4.y + wv4.z * uv4.z + wv4.w * uv4.w;
        }
    }
    float mm = dot;
    mm = fmaxf(mm, __shfl_xor(mm, 16));
    mm = fmaxf(mm, __shfl_xor(mm, 8));
    mm = fmaxf(mm, __shfl_xor(mm, 4));
    mm = fmaxf(mm, __shfl_xor(mm, 2));
    mm = fmaxf(mm, __shfl_xor(mm, 1));
    float ex = __expf(dot - mm);
    float sm = ex;
    sm += __shfl_xor(sm, 16);
    sm += __shfl_xor(sm, 8);
    sm += __shfl_xor(sm, 4);
    sm += __shfl_xor(sm, 2);
    sm += __shfl_xor(sm, 1);
    if (lane < N_REL) s_score[wv][lane] = ex / sm;
    // no barrier: s_score[wv] is produced and consumed by this wave only

    float proj = 0.f;
    const float4* sc4 = (const float4*)s_score[wv];
#pragma unroll
    for (int q = 0; q < 8; ++q) {
        float4 s4 = sc4[q];   // broadcast read (same addr all lanes)
        proj += s4.x * wreg[4 * q]     + s4.y * wreg[4 * q + 1]
              + s4.z * wreg[4 * q + 2] + s4.w * wreg[4 * q + 3];
    }

    uagg[(size_t)u * D + dim] = tot * (1.f + proj);
}

extern "C" void kernel_launch(void* const* d_in, const int* in_sizes, int n_in,
                              void* d_out, int out_size, void* d_ws, size_t ws_size,
                              hipStream_t stream) {
    const float* cat   = (const float*)d_in[0];
    const float* uemb  = (const float*)d_in[1];
    const int*   eidx  = (const int*)d_in[2];
    const int*   etype = (const int*)d_in[3];
    const int*   imr   = (const int*)d_in[4];
    const int*   imc   = (const int*)d_in[5];
    const float* imv   = (const float*)d_in[6];
    const float* W     = (const float*)d_in[7];
    const int* head = eidx;
    const int* tail = eidx + NEDGE;

    float* out     = (float*)d_out;
    float* cat_agg = out;                         // [N_CAT, D]
    float* uagg    = out + (size_t)N_CAT * D;     // [N_USERS, D]

    float* norm2   = (float*)d_ws;
    int*   ccnt    = (int*)(norm2 + (size_t)N_CAT * N_REL);
    int*   cbase_e = ccnt + NBK;
    int*   cbase_u = cbase_e + NBKE + 1;
    int*   ccur_e  = cbase_u + NBKU + 1;
    int*   ccur_u  = ccur_e + NBKE;
    int*   offs_e  = ccur_u + NBKU;
    int*   offs_u  = offs_e + N_CAT + 1;
    int*   sorted_ta = offs_u + N_USERS + 1;
    int2*  sorted_cv = (int2*)(sorted_ta + NEDGE);

    unsigned short* cath_us =
        (unsigned short*)(((uintptr_t)(sorted_cv + NNZ) + 255) & ~(uintptr_t)255);
    size_t need = (size_t)((char*)(cath_us + (size_t)N_CAT * D) - (char*)d_ws);
    int use16 = (ws_size >= need);

    hipMemsetAsync(ccnt, 0, (size_t)NBK * sizeof(int), stream);

    coarse_hist_kernel<<<512, 256, 0, stream>>>(head, imr, ccnt);
    coarse_scan_kernel<<<1, 256, 0, stream>>>(ccnt, cbase_e, cbase_u,
                                              ccur_e, ccur_u, offs_e, offs_u);
    pass1_edges_kernel<<<(NEDGE + T1 - 1) / T1, 256, 0, stream>>>(
        head, tail, etype, ccur_e, sorted_ta);
    pass1_users_kernel<<<(NNZ + T1 - 1) / T1, 256, 0, stream>>>(
        imr, imc, imv, ccur_u, sorted_cv);
    pass2_kernel<<<NBK, 256, 0, stream>>>(cbase_e, cbase_u, offs_e, offs_u,
                                          sorted_ta, sorted_cv);
    if (use16) {
        norm2_kernel<1><<<(N_CAT + 63) / 64, 256, 0, stream>>>(cat, W, norm2, cath_us);
        cat_agg_sorted_kernel<1><<<N_CAT / 4, 256, 0, stream>>>(
            offs_e, sorted_ta, norm2, cat, (const uint4*)cath_us, W, cat_agg);
        spmm_user_kernel<1><<<N_USERS / 4, 256, 0, stream>>>(
            offs_u, sorted_cv, cat, (const uint4*)cath_us, uemb, W, uagg);
    } else {
        norm2_kernel<0><<<(N_CAT + 63) / 64, 256, 0, stream>>>(cat, W, norm2, nullptr);
        cat_agg_sorted_kernel<0><<<N_CAT / 4, 256, 0, stream>>>(
            offs_e, sorted_ta, norm2, cat, nullptr, W, cat_agg);
        spmm_user_kernel<0><<<N_USERS / 4, 256, 0, stream>>>(
            offs_u, sorted_cv, cat, nullptr, uemb, W, uagg);
    }
}

// Round 5
// 378.195 us; speedup vs baseline: 1.2609x; 1.2609x over previous
//
#include <hip/hip_runtime.h>
#include <hip/hip_bf16.h>
#include <hip/hip_fp16.h>
#include <float.h>
#include <stdint.h>

#define N_CAT   100000
#define N_USERS 50000
#define N_REL   32
#define D       64
#define NEDGE   1600000
#define NNZ     1000000

#define EB_SHIFT 9
#define EB_SIZE  512
#define NBKE     ((N_CAT + EB_SIZE - 1) / EB_SIZE)    // 196 edge buckets
#define UB_SHIFT 8
#define UB_SIZE  256
#define NBKU     ((N_USERS + UB_SIZE - 1) / UB_SIZE)  // 196 user buckets
#define NBK      (NBKE + NBKU)                        // 392

#define T1   4096      // pass1 tile (16 recs/thread @ 256 threads)
#define ECAP 15360     // pass2 edge bucket LDS capacity
#define UCAP 7680      // pass2 user bucket LDS capacity

// LDS W row stride in float4 (68 floats): breaks the "every 256B row starts at
// bank 0" 8-way conflict down to <=4-way for grouped ds_read_b128.
#define WSTRIDE 17

// ---------------------------------------------------------------------------
// ws: norm2[N_CAT*32] f32 | ccnt[392] | cbase_e[197] | cbase_u[197] |
//     ccur_e[196] | ccur_u[196] | offs_e[100001] | offs_u[50001] |
//     sorted_ta[NEDGE] int | sorted_cv[NNZ] int2 | cat_f16[N_CAT*64] (aligned)
// scale[u][d] = 1 + (softmax(u.W^T)@W)[d] is precomputed INTO uagg (d_out)
// by scale_kernel; spmm multiplies in place. No extra ws needed.
// ---------------------------------------------------------------------------

__device__ __forceinline__ unsigned int pack_half2(float a, float b) {
    return (unsigned int)__half_as_ushort(__float2half_rn(a)) |
           ((unsigned int)__half_as_ushort(__float2half_rn(b)) << 16);
}

// Gather one 64-dim row, 8 lanes x 8 dims. F16: one uint4 = one 128B line.
template<int F16>
__device__ __forceinline__ void load_row8(const float4* __restrict__ catv4,
                                          const uint4* __restrict__ cath4,
                                          int row, int gl, float f[8]) {
    if (F16) {
        uint4 h = cath4[(size_t)row * 8 + gl];
        const __half2* hp = (const __half2*)&h;
        float2 a = __half22float2(hp[0]);
        float2 b = __half22float2(hp[1]);
        float2 c = __half22float2(hp[2]);
        float2 d = __half22float2(hp[3]);
        f[0] = a.x; f[1] = a.y; f[2] = b.x; f[3] = b.y;
        f[4] = c.x; f[5] = c.y; f[6] = d.x; f[7] = d.y;
    } else {
        float4 a = catv4[(size_t)row * 16 + gl * 2];
        float4 b = catv4[(size_t)row * 16 + gl * 2 + 1];
        f[0] = a.x; f[1] = a.y; f[2] = a.z; f[3] = a.w;
        f[4] = b.x; f[5] = b.y; f[6] = b.z; f[7] = b.w;
    }
}

// Butterfly reduce-scatter over the 8 groups (7 shfl, HW-validated round 4):
// lane ends with the full sum of dim (lane&7)*8 + brev3(lane>>3).
__device__ __forceinline__ float reduce_scatter8(const float a[8], int lane) {
    int b3 = (lane >> 3) & 1, b4 = (lane >> 4) & 1, b5 = (lane >> 5) & 1;
    float r[4];
#pragma unroll
    for (int j = 0; j < 4; ++j) {
        float x = b3 ? a[j] : a[j + 4];
        float k = b3 ? a[j + 4] : a[j];
        r[j] = k + __shfl_xor(x, 8);
    }
    float s[2];
#pragma unroll
    for (int j = 0; j < 2; ++j) {
        float x = b4 ? r[j] : r[j + 2];
        float k = b4 ? r[j + 2] : r[j];
        s[j] = k + __shfl_xor(x, 16);
    }
    float x = b5 ? s[0] : s[1];
    float k = b5 ? s[1] : s[0];
    return k + __shfl_xor(x, 32);
}

__device__ __forceinline__ int dim_of_lane(int lane) {
    int g = lane >> 3;
    return ((lane & 7) << 3) | ((g & 1) << 2) | (g & 2) | (g >> 2);
}

// norm2[n][r] = sum_d cat[n][d]^2 * W[r][d]^2.
template<int W16>
__global__ __launch_bounds__(256) void norm2_kernel(
        const float* __restrict__ cat,
        const float* __restrict__ W,
        float* __restrict__ norm2,
        unsigned short* __restrict__ cath) {
    __shared__ float4 w2[N_REL * 16];   // squared W, 8 KB
    int t = threadIdx.x;
    const float4* Wv = (const float4*)W;
    for (int i = t; i < N_REL * 16; i += 256) {
        float4 v = Wv[i];
        v.x *= v.x; v.y *= v.y; v.z *= v.z; v.w *= v.w;
        w2[i] = v;
    }
    __syncthreads();

    int node = blockIdx.x * 64 + (t >> 2);
    int q    = t & 3;
    if (node >= N_CAT) return;

    const float4* catv = (const float4*)cat;
    float acc[N_REL];
#pragma unroll
    for (int r = 0; r < N_REL; ++r) acc[r] = 0.f;

    uint2 hp[4];
#pragma unroll
    for (int c = 0; c < 4; ++c) {
        float4 xv = catv[(size_t)node * 16 + q * 4 + c];
        if (W16) {
            hp[c].x = pack_half2(xv.x, xv.y);
            hp[c].y = pack_half2(xv.z, xv.w);
        }
        xv.x *= xv.x; xv.y *= xv.y; xv.z *= xv.z; xv.w *= xv.w;
#pragma unroll
        for (int r = 0; r < N_REL; ++r) {
            float4 wv = w2[r * 16 + q * 4 + c];
            acc[r] += xv.x * wv.x + xv.y * wv.y + xv.z * wv.z + xv.w * wv.w;
        }
    }
    if (W16) {
        uint4* cv16 = (uint4*)cath;
        cv16[(size_t)node * 8 + q * 2]     = make_uint4(hp[0].x, hp[0].y, hp[1].x, hp[1].y);
        cv16[(size_t)node * 8 + q * 2 + 1] = make_uint4(hp[2].x, hp[2].y, hp[3].x, hp[3].y);
    }
#pragma unroll
    for (int r = 0; r < N_REL; ++r) {
        acc[r] += __shfl_xor(acc[r], 1);
        acc[r] += __shfl_xor(acc[r], 2);
    }
    float4* nv = (float4*)norm2;
    size_t base = (size_t)node * 8 + q * 2;
    if (q == 0) {
        nv[base]     = make_float4(acc[0],  acc[1],  acc[2],  acc[3]);
        nv[base + 1] = make_float4(acc[4],  acc[5],  acc[6],  acc[7]);
    } else if (q == 1) {
        nv[base]     = make_float4(acc[8],  acc[9],  acc[10], acc[11]);
        nv[base + 1] = make_float4(acc[12], acc[13], acc[14], acc[15]);
    } else if (q == 2) {
        nv[base]     = make_float4(acc[16], acc[17], acc[18], acc[19]);
        nv[base + 1] = make_float4(acc[20], acc[21], acc[22], acc[23]);
    } else {
        nv[base]     = make_float4(acc[24], acc[25], acc[26], acc[27]);
        nv[base + 1] = make_float4(acc[28], acc[29], acc[30], acc[31]);
    }
}

// per-WG LDS histogram over 392 coarse buckets, single flush
__global__ void coarse_hist_kernel(const int* __restrict__ head,
                                   const int* __restrict__ imr,
                                   int* __restrict__ ccnt) {
    __shared__ int h[NBK];
    int t = threadIdx.x;
    for (int i = t; i < NBK; i += 256) h[i] = 0;
    __syncthreads();
    int stride = gridDim.x * 256;
    for (int i = blockIdx.x * 256 + t; i < NEDGE + NNZ; i += stride) {
        if (i < NEDGE) atomicAdd(&h[head[i] >> EB_SHIFT], 1);
        else           atomicAdd(&h[NBKE + (imr[i - NEDGE] >> UB_SHIFT)], 1);
    }
    __syncthreads();
    for (int i = t; i < NBK; i += 256) if (h[i]) atomicAdd(&ccnt[i], h[i]);
}

// single-WG scan of 392 coarse bins -> bucket bases + cursors + sentinels
__global__ void coarse_scan_kernel(const int* __restrict__ ccnt,
                                   int* __restrict__ cbase_e, int* __restrict__ cbase_u,
                                   int* __restrict__ ccur_e,  int* __restrict__ ccur_u,
                                   int* __restrict__ offs_e,  int* __restrict__ offs_u) {
    __shared__ int sc[256];
    int t = threadIdx.x;
    int c = (t < NBKE) ? ccnt[t] : 0;
    sc[t] = c; __syncthreads();
    for (int off = 1; off < 256; off <<= 1) {
        int v = (t >= off) ? sc[t - off] : 0; __syncthreads();
        sc[t] += v; __syncthreads();
    }
    int excl = sc[t] - c;
    if (t < NBKE) { cbase_e[t] = excl; ccur_e[t] = excl; }
    if (t == NBKE - 1) cbase_e[NBKE] = excl + c;
    __syncthreads();
    c = (t < NBKU) ? ccnt[NBKE + t] : 0;
    sc[t] = c; __syncthreads();
    for (int off = 1; off < 256; off <<= 1) {
        int v = (t >= off) ? sc[t - off] : 0; __syncthreads();
        sc[t] += v; __syncthreads();
    }
    excl = sc[t] - c;
    if (t < NBKU) { cbase_u[t] = excl; ccur_u[t] = excl; }
    if (t == NBKU - 1) cbase_u[NBKU] = excl + c;
    if (t == 0) { offs_e[N_CAT] = NEDGE; offs_u[N_USERS] = NNZ; }
}

// pass1 edges: tile -> LDS count/scan -> ONE global atomic per (tile,bucket)
__global__ __launch_bounds__(256) void pass1_edges_kernel(
        const int* __restrict__ head, const int* __restrict__ tail,
        const int* __restrict__ etype, int* __restrict__ ccur_e,
        int* __restrict__ sorted_ta) {
    __shared__ int cnt[256], loc[256], base[256], sc[256];
    __shared__ int stage[T1];
    __shared__ int gpos[T1];
    int t = threadIdx.x;
    int tile = blockIdx.x * T1;
    cnt[t] = 0;
    __syncthreads();
    int rec[16], bk[16];
#pragma unroll
    for (int k = 0; k < 16; ++k) {
        int i = tile + k * 256 + t;
        if (i < NEDGE) {
            int h = head[i], tl = tail[i], r = etype[i] - 1;
            bk[k]  = h >> EB_SHIFT;
            rec[k] = ((h & (EB_SIZE - 1)) << 22) | (tl << 5) | r;
            atomicAdd(&cnt[bk[k]], 1);
        } else bk[k] = -1;
    }
    __syncthreads();
    int c = cnt[t];
    sc[t] = c; __syncthreads();
    for (int off = 1; off < 256; off <<= 1) {
        int v = (t >= off) ? sc[t - off] : 0; __syncthreads();
        sc[t] += v; __syncthreads();
    }
    loc[t] = sc[t] - c;
    if (t < NBKE && c > 0) base[t] = atomicAdd(&ccur_e[t], c);
    __syncthreads();
    cnt[t] = loc[t];
    __syncthreads();
#pragma unroll
    for (int k = 0; k < 16; ++k) {
        if (bk[k] >= 0) {
            int p = atomicAdd(&cnt[bk[k]], 1);
            stage[p] = rec[k];
            gpos[p]  = base[bk[k]] + (p - loc[bk[k]]);
        }
    }
    __syncthreads();
    int nv = min(T1, NEDGE - tile);
    for (int i = t; i < nv; i += 256) sorted_ta[gpos[i]] = stage[i];
}

__global__ __launch_bounds__(256) void pass1_users_kernel(
        const int* __restrict__ imr, const int* __restrict__ imc,
        const float* __restrict__ imv, int* __restrict__ ccur_u,
        int2* __restrict__ sorted_cv) {
    __shared__ int cnt[256], loc[256], base[256], sc[256];
    __shared__ int2 stage[T1];
    __shared__ int gpos[T1];
    int t = threadIdx.x;
    int tile = blockIdx.x * T1;
    cnt[t] = 0;
    __syncthreads();
    int2 rec[16]; int bk[16];
#pragma unroll
    for (int k = 0; k < 16; ++k) {
        int i = tile + k * 256 + t;
        if (i < NNZ) {
            int rr = imr[i];
            bk[k]  = rr >> UB_SHIFT;
            rec[k] = make_int2(((rr & (UB_SIZE - 1)) << 17) | imc[i],
                               __float_as_int(imv[i]));
            atomicAdd(&cnt[bk[k]], 1);
        } else bk[k] = -1;
    }
    __syncthreads();
    int c = cnt[t];
    sc[t] = c; __syncthreads();
    for (int off = 1; off < 256; off <<= 1) {
        int v = (t >= off) ? sc[t - off] : 0; __syncthreads();
        sc[t] += v; __syncthreads();
    }
    loc[t] = sc[t] - c;
    if (t < NBKU && c > 0) base[t] = atomicAdd(&ccur_u[t], c);
    __syncthreads();
    cnt[t] = loc[t];
    __syncthreads();
#pragma unroll
    for (int k = 0; k < 16; ++k) {
        if (bk[k] >= 0) {
            int p = atomicAdd(&cnt[bk[k]], 1);
            stage[p] = rec[k];
            gpos[p]  = base[bk[k]] + (p - loc[bk[k]]);
        }
    }
    __syncthreads();
    int nv = min(T1, NNZ - tile);
    for (int i = t; i < nv; i += 256) sorted_cv[gpos[i]] = stage[i];
}

// pass2: one WG per coarse bucket; fine counting-sort in LDS; writes fine offs
__global__ __launch_bounds__(256) void pass2_kernel(
        const int* __restrict__ cbase_e, const int* __restrict__ cbase_u,
        int* __restrict__ offs_e, int* __restrict__ offs_u,
        int* __restrict__ sorted_ta, int2* __restrict__ sorted_cv) {
    __shared__ int lds[UCAP * 2];        // 60 KB
    __shared__ int fh[EB_SIZE + 1];
    __shared__ int sc[256];
    int t = threadIdx.x;
    int b = blockIdx.x;
    if (b < NBKE) {
        int h0 = b << EB_SHIFT;
        int start = cbase_e[b], end = cbase_e[b + 1];
        int n = min(end - start, ECAP);
        for (int i = t; i < n; i += 256) lds[i] = sorted_ta[start + i];
        fh[2 * t] = 0; fh[2 * t + 1] = 0;
        __syncthreads();
        for (int i = t; i < n; i += 256) atomicAdd(&fh[lds[i] >> 22], 1);
        __syncthreads();
        int a = fh[2 * t], b2 = fh[2 * t + 1];
        sc[t] = a + b2; __syncthreads();
        for (int off = 1; off < 256; off <<= 1) {
            int v = (t >= off) ? sc[t - off] : 0; __syncthreads();
            sc[t] += v; __syncthreads();
        }
        int pe = sc[t] - (a + b2);
        int lim = min(EB_SIZE, N_CAT - h0);
        if (2 * t     < lim) offs_e[h0 + 2 * t]     = start + pe;
        if (2 * t + 1 < lim) offs_e[h0 + 2 * t + 1] = start + pe + a;
        fh[2 * t] = pe; fh[2 * t + 1] = pe + a;
        __syncthreads();
        for (int i = t; i < n; i += 256) {
            int rec = lds[i];
            int p = atomicAdd(&fh[rec >> 22], 1);
            sorted_ta[start + p] = rec & 0x3FFFFF;     // (tail<<5)|rel
        }
    } else {
        int k = b - NBKE;
        int u0 = k << UB_SHIFT;
        int start = cbase_u[k], end = cbase_u[k + 1];
        int n = min(end - start, UCAP);
        int2* lds2 = (int2*)lds;
        for (int i = t; i < n; i += 256) lds2[i] = sorted_cv[start + i];
        fh[t] = 0;
        __syncthreads();
        for (int i = t; i < n; i += 256) atomicAdd(&fh[lds2[i].x >> 17], 1);
        __syncthreads();
        int c = fh[t];
        sc[t] = c; __syncthreads();
        for (int off = 1; off < 256; off <<= 1) {
            int v = (t >= off) ? sc[t - off] : 0; __syncthreads();
            sc[t] += v; __syncthreads();
        }
        int excl = sc[t] - c;
        int lim = min(UB_SIZE, N_USERS - u0);
        if (t < lim) offs_u[u0 + t] = start + excl;
        fh[t] = excl;
        __syncthreads();
        for (int i = t; i < n; i += 256) {
            int2 rec = lds2[i];
            int p = atomicAdd(&fh[rec.x >> 17], 1);
            sorted_cv[start + p] = make_int2(rec.x & 0x1FFFF, rec.y);
        }
    }
}

#define FMA8(ACC, WS, F, W0, W1)                                         \
    ACC[0] += WS * F[0] * W0.x;  ACC[1] += WS * F[1] * W0.y;             \
    ACC[2] += WS * F[2] * W0.z;  ACC[3] += WS * F[3] * W0.w;             \
    ACC[4] += WS * F[4] * W1.x;  ACC[5] += WS * F[5] * W1.y;             \
    ACC[6] += WS * F[6] * W1.z;  ACC[7] += WS * F[7] * W1.w;

// scale[u][d] = 1 + (softmax(uemb[u]@W^T) @ W)[d], written into uagg.
// One THREAD per user: all W traffic is LDS broadcast, softmax is purely
// in-register (no cross-lane at all). ~780 waves total -> ~5 us.
__global__ __launch_bounds__(256) void scale_kernel(
        const float* __restrict__ uemb,
        const float* __restrict__ W,
        float* __restrict__ uagg) {
    __shared__ float sWt[D][N_REL + 4];   // W^T, stride 36 floats (16B-aligned)
    int t = threadIdx.x;
    for (int i = t; i < N_REL * D; i += 256) {
        int r = i >> 6, d = i & 63;
        sWt[d][r] = W[i];
    }
    __syncthreads();
    int u = blockIdx.x * 256 + t;
    if (u >= N_USERS) return;

    const float4* ur4 = (const float4*)(uemb + (size_t)u * D);
    float dot[N_REL];
#pragma unroll
    for (int r = 0; r < N_REL; ++r) dot[r] = 0.f;
#pragma unroll
    for (int d4 = 0; d4 < 16; ++d4) {
        float4 uv = ur4[d4];
        float us[4] = {uv.x, uv.y, uv.z, uv.w};
#pragma unroll
        for (int k = 0; k < 4; ++k) {
            const float4* wt4 = (const float4*)sWt[d4 * 4 + k];
#pragma unroll
            for (int r4 = 0; r4 < 8; ++r4) {
                float4 w4 = wt4[r4];
                dot[4 * r4]     += us[k] * w4.x;
                dot[4 * r4 + 1] += us[k] * w4.y;
                dot[4 * r4 + 2] += us[k] * w4.z;
                dot[4 * r4 + 3] += us[k] * w4.w;
            }
        }
    }
    // in-register softmax over 32 rels
    float m = dot[0];
#pragma unroll
    for (int r = 1; r < N_REL; ++r) m = fmaxf(m, dot[r]);
    float s = 0.f;
#pragma unroll
    for (int r = 0; r < N_REL; ++r) { dot[r] = __expf(dot[r] - m); s += dot[r]; }
    float inv = 1.f / s;

    float4* out4 = (float4*)(uagg + (size_t)u * D);
#pragma unroll
    for (int d4 = 0; d4 < 16; ++d4) {
        float p[4];
#pragma unroll
        for (int k = 0; k < 4; ++k) {
            const float4* wt4 = (const float4*)sWt[d4 * 4 + k];
            float acc = 0.f;
#pragma unroll
            for (int r4 = 0; r4 < 8; ++r4) {
                float4 w4 = wt4[r4];
                acc += dot[4 * r4] * w4.x + dot[4 * r4 + 1] * w4.y
                     + dot[4 * r4 + 2] * w4.z + dot[4 * r4 + 3] * w4.w;
            }
            p[k] = 1.f + acc * inv;
        }
        out4[d4] = make_float4(p[0], p[1], p[2], p[3]);
    }
}

// one wave per head (round-3 proven body). Output: 7-shfl reduce-scatter +
// wave-private LDS transpose + single coalesced float4 store by 16 lanes
// (replaces the 24-shfl all-reduce).
template<int F16>
__global__ __launch_bounds__(256, 4) void cat_agg_sorted_kernel(
        const int* __restrict__ offs_e,
        const int* __restrict__ sorted_ta,
        const float* __restrict__ norm2,
        const float* __restrict__ cat,
        const uint4* __restrict__ cath4,
        const float* __restrict__ W,
        float* __restrict__ cat_agg) {
    __shared__ float4 sW4[N_REL * WSTRIDE];   // 8704 B
    __shared__ float  scr[4][D];              // 1 KB transpose scratch
    {
        const float4* Wv = (const float4*)W;
        for (int i = threadIdx.x; i < N_REL * 16; i += 256)
            sW4[(i >> 4) * WSTRIDE + (i & 15)] = Wv[i];
    }
    __syncthreads();

    const float4* catv4 = (const float4*)cat;
    int wv   = threadIdx.x >> 6;
    int lane = threadIdx.x & 63;
    int grp  = lane >> 3;
    int gl   = lane & 7;
    int h = blockIdx.x * 4 + wv;
    int start = offs_e[h];
    int end   = offs_e[h + 1];
    int deg   = end - start;

    float accA[8], accB[8];
#pragma unroll
    for (int k = 0; k < 8; ++k) { accA[k] = 0.f; accB[k] = 0.f; }

    if (deg <= 32) {
        int rec = 0;
        if (lane < deg) rec = sorted_ta[start + lane];
        int tt = rec >> 5, r = rec & 31;
        float n2t = norm2[(size_t)tt * N_REL + r];
        float n2h = norm2[(size_t)h  * N_REL + r];

        // prefetch row data NOW (overlaps softmax shfl chain)
        int tA0 = __shfl(rec, grp),      tB0 = __shfl(rec, 8 + grp);
        float fA0[8], fB0[8], fA1[8], fB1[8];
        load_row8<F16>(catv4, cath4, tA0 >> 5, gl, fA0);
        load_row8<F16>(catv4, cath4, tB0 >> 5, gl, fB0);
        int tA1 = 0, tB1 = 0;
        if (deg > 16) {
            tA1 = __shfl(rec, 16 + grp); tB1 = __shfl(rec, 24 + grp);
            load_row8<F16>(catv4, cath4, tA1 >> 5, gl, fA1);
            load_row8<F16>(catv4, cath4, tB1 >> 5, gl, fB1);
        }

        float att = (lane < deg) ? n2h * n2t : -FLT_MAX;
        float m = att;
        m = fmaxf(m, __shfl_xor(m, 1));
        m = fmaxf(m, __shfl_xor(m, 2));
        m = fmaxf(m, __shfl_xor(m, 4));
        m = fmaxf(m, __shfl_xor(m, 8));
        if (deg > 16) m = fmaxf(m, __shfl_xor(m, 16));
        float ex = (lane < deg) ? __expf(att - m) : 0.f;
        float ssum = ex;
        ssum += __shfl_xor(ssum, 1);
        ssum += __shfl_xor(ssum, 2);
        ssum += __shfl_xor(ssum, 4);
        ssum += __shfl_xor(ssum, 8);
        if (deg > 16) ssum += __shfl_xor(ssum, 16);
        float w = (deg > 0) ? ex / ssum : 0.f;

        float wA0 = __shfl(w, grp), wB0 = __shfl(w, 8 + grp);
        const float4* wrA0 = &sW4[(tA0 & 31) * WSTRIDE + gl * 2];
        const float4* wrB0 = &sW4[(tB0 & 31) * WSTRIDE + gl * 2];
        float4 wa00 = wrA0[0], wa01 = wrA0[1];
        float4 wb00 = wrB0[0], wb01 = wrB0[1];
        FMA8(accA, wA0, fA0, wa00, wa01)
        FMA8(accB, wB0, fB0, wb00, wb01)
        if (deg > 16) {
            float wA1 = __shfl(w, 16 + grp), wB1 = __shfl(w, 24 + grp);
            const float4* wrA1 = &sW4[(tA1 & 31) * WSTRIDE + gl * 2];
            const float4* wrB1 = &sW4[(tB1 & 31) * WSTRIDE + gl * 2];
            float4 wa10 = wrA1[0], wa11 = wrA1[1];
            float4 wb10 = wrB1[0], wb11 = wrB1[1];
            FMA8(accA, wA1, fA1, wa10, wa11)
            FMA8(accB, wB1, fB1, wb10, wb11)
        }
    } else if (deg <= 64) {
        int   rec = 0;
        float att = -FLT_MAX;
        if (lane < deg) {
            rec = sorted_ta[start + lane];
            int tt = rec >> 5, r = rec & 31;
            att = norm2[h * N_REL + r] * norm2[(size_t)tt * N_REL + r];
        }
        float m = att;
#pragma unroll
        for (int off = 32; off > 0; off >>= 1) m = fmaxf(m, __shfl_xor(m, off));
        float ex = (lane < deg) ? __expf(att - m) : 0.f;
        float ssum = ex;
#pragma unroll
        for (int off = 32; off > 0; off >>= 1) ssum += __shfl_xor(ssum, off);
        float w = (deg > 0) ? ex / ssum : 0.f;

        for (int e = 0; e < deg; e += 16) {
            int   tA = __shfl(rec, e + grp);
            float wA = __shfl(w,   e + grp);
            int   tB = __shfl(rec, e + 8 + grp);
            float wB = __shfl(w,   e + 8 + grp);
            float fA[8], fB[8];
            load_row8<F16>(catv4, cath4, tA >> 5, gl, fA);
            load_row8<F16>(catv4, cath4, tB >> 5, gl, fB);
            const float4* wrA = &sW4[(tA & 31) * WSTRIDE + gl * 2];
            const float4* wrB = &sW4[(tB & 31) * WSTRIDE + gl * 2];
            float4 wa0 = wrA[0], wa1 = wrA[1];
            float4 wb0 = wrB[0], wb1 = wrB[1];
            FMA8(accA, wA, fA, wa0, wa1)
            FMA8(accB, wB, fB, wb0, wb1)
        }
    } else {
        float m = -FLT_MAX;
        for (int j = lane; j < deg; j += 64) {
            int rec = sorted_ta[start + j];
            int tt = rec >> 5, r = rec & 31;
            m = fmaxf(m, norm2[h * N_REL + r] * norm2[(size_t)tt * N_REL + r]);
        }
#pragma unroll
        for (int off = 32; off > 0; off >>= 1) m = fmaxf(m, __shfl_xor(m, off));
        float ssum = 0.f;
        for (int j = lane; j < deg; j += 64) {
            int rec = sorted_ta[start + j];
            int tt = rec >> 5, r = rec & 31;
            ssum += __expf(norm2[h * N_REL + r] * norm2[(size_t)tt * N_REL + r] - m);
        }
#pragma unroll
        for (int off = 32; off > 0; off >>= 1) ssum += __shfl_xor(ssum, off);
        float inv = 1.f / ssum;
        for (int j0 = 0; j0 < deg; j0 += 64) {
            int n = min(64, deg - j0);
            int   rec = 0;
            float w   = 0.f;
            if (lane < n) {
                rec = sorted_ta[start + j0 + lane];
                int tt = rec >> 5, r = rec & 31;
                w = __expf(norm2[h * N_REL + r] * norm2[(size_t)tt * N_REL + r] - m) * inv;
            }
            for (int e = 0; e < n; e += 16) {
                int   tA = __shfl(rec, e + grp);
                float wA = __shfl(w,   e + grp);
                int   tB = __shfl(rec, e + 8 + grp);
                float wB = __shfl(w,   e + 8 + grp);
                float fA[8], fB[8];
                load_row8<F16>(catv4, cath4, tA >> 5, gl, fA);
                load_row8<F16>(catv4, cath4, tB >> 5, gl, fB);
                const float4* wrA = &sW4[(tA & 31) * WSTRIDE + gl * 2];
                const float4* wrB = &sW4[(tB & 31) * WSTRIDE + gl * 2];
                float4 wa0 = wrA[0], wa1 = wrA[1];
                float4 wb0 = wrB[0], wb1 = wrB[1];
                FMA8(accA, wA, fA, wa0, wa1)
                FMA8(accB, wB, fB, wb0, wb1)
            }
        }
    }

    float a[8];
#pragma unroll
    for (int k = 0; k < 8; ++k) a[k] = accA[k] + accB[k];
    float tot = reduce_scatter8(a, lane);
    scr[wv][dim_of_lane(lane)] = tot;         // 2-way bank alias: free
    // wave-private exchange: in-wave LDS ops are ordered; no barrier needed
    if (lane < 16) {
        float4 o = ((const float4*)scr[wv])[lane];
        ((float4*)&cat_agg[(size_t)h * D])[lane] = o;
    }
}

// spmm: gather + reduce-scatter only; epilogue is one coalesced multiply by
// the precomputed scale (read from uagg in place). ~17 DS ops/wave (was 174).
template<int F16>
__global__ __launch_bounds__(256, 4) void spmm_user_kernel(
        const int* __restrict__ offs_u,
        const int2* __restrict__ sorted_cv,
        const float* __restrict__ cat,
        const uint4* __restrict__ cath4,
        float* __restrict__ uagg) {
    __shared__ float scr[4][D];               // 1 KB
    const float4* catv4 = (const float4*)cat;
    int wv   = threadIdx.x >> 6;
    int lane = threadIdx.x & 63;
    int grp  = lane >> 3;
    int gl   = lane & 7;
    int u = blockIdx.x * 4 + wv;
    int start = offs_u[u];
    int end   = offs_u[u + 1];
    int deg   = end - start;

    float accA[8], accB[8];
#pragma unroll
    for (int k = 0; k < 8; ++k) { accA[k] = 0.f; accB[k] = 0.f; }

    if (deg <= 32) {
        int my_c = 0; float my_v = 0.f;
        if (lane < deg) {
            int2 cv = sorted_cv[start + lane];
            my_c = cv.x;
            my_v = __int_as_float(cv.y);
        }
        int   cA0 = __shfl(my_c, grp),     cB0 = __shfl(my_c, 8 + grp);
        float vA0 = __shfl(my_v, grp),     vB0 = __shfl(my_v, 8 + grp);
        float fA0[8], fB0[8], fA1[8], fB1[8];
        load_row8<F16>(catv4, cath4, cA0, gl, fA0);
        load_row8<F16>(catv4, cath4, cB0, gl, fB0);
        float vA1 = 0.f, vB1 = 0.f;
        if (deg > 16) {
            int cA1 = __shfl(my_c, 16 + grp), cB1 = __shfl(my_c, 24 + grp);
            vA1 = __shfl(my_v, 16 + grp); vB1 = __shfl(my_v, 24 + grp);
            load_row8<F16>(catv4, cath4, cA1, gl, fA1);
            load_row8<F16>(catv4, cath4, cB1, gl, fB1);
#pragma unroll
            for (int k = 0; k < 8; ++k) {
                accA[k] += vA1 * fA1[k];
                accB[k] += vB1 * fB1[k];
            }
        }
#pragma unroll
        for (int k = 0; k < 8; ++k) {
            accA[k] += vA0 * fA0[k];
            accB[k] += vB0 * fB0[k];
        }
    } else {
        for (int j0 = 0; j0 < deg; j0 += 64) {
            int n = min(64, deg - j0);
            int   my_c = 0;
            float my_v = 0.f;
            if (lane < n) {
                int2 cv = sorted_cv[start + j0 + lane];
                my_c = cv.x;
                my_v = __int_as_float(cv.y);
            }
            for (int e = 0; e < n; e += 16) {
                int   cA = __shfl(my_c, e + grp);
                float vA = __shfl(my_v, e + grp);
                int   cB = __shfl(my_c, e + 8 + grp);
                float vB = __shfl(my_v, e + 8 + grp);
                float fA[8], fB[8];
                load_row8<F16>(catv4, cath4, cA, gl, fA);
                load_row8<F16>(catv4, cath4, cB, gl, fB);
#pragma unroll
                for (int k = 0; k < 8; ++k) {
                    accA[k] += vA * fA[k];
                    accB[k] += vB * fB[k];
                }
            }
        }
    }

    float a[8];
#pragma unroll
    for (int k = 0; k < 8; ++k) a[k] = accA[k] + accB[k];
    float tot = reduce_scatter8(a, lane);
    scr[wv][dim_of_lane(lane)] = tot;
    if (lane < 16) {
        float4 o = ((const float4*)scr[wv])[lane];
        float4* row = (float4*)&uagg[(size_t)u * D];
        float4 s = row[lane];                 // scale = 1 + proj (precomputed)
        row[lane] = make_float4(o.x * s.x, o.y * s.y, o.z * s.z, o.w * s.w);
    }
}

extern "C" void kernel_launch(void* const* d_in, const int* in_sizes, int n_in,
                              void* d_out, int out_size, void* d_ws, size_t ws_size,
                              hipStream_t stream) {
    const float* cat   = (const float*)d_in[0];
    const float* uemb  = (const float*)d_in[1];
    const int*   eidx  = (const int*)d_in[2];
    const int*   etype = (const int*)d_in[3];
    const int*   imr   = (const int*)d_in[4];
    const int*   imc   = (const int*)d_in[5];
    const float* imv   = (const float*)d_in[6];
    const float* W     = (const float*)d_in[7];
    const int* head = eidx;
    const int* tail = eidx + NEDGE;

    float* out     = (float*)d_out;
    float* cat_agg = out;                         // [N_CAT, D]
    float* uagg    = out + (size_t)N_CAT * D;     // [N_USERS, D]

    float* norm2   = (float*)d_ws;
    int*   ccnt    = (int*)(norm2 + (size_t)N_CAT * N_REL);
    int*   cbase_e = ccnt + NBK;
    int*   cbase_u = cbase_e + NBKE + 1;
    int*   ccur_e  = cbase_u + NBKU + 1;
    int*   ccur_u  = ccur_e + NBKE;
    int*   offs_e  = ccur_u + NBKU;
    int*   offs_u  = offs_e + N_CAT + 1;
    int*   sorted_ta = offs_u + N_USERS + 1;
    int2*  sorted_cv = (int2*)(sorted_ta + NEDGE);

    unsigned short* cath_us =
        (unsigned short*)(((uintptr_t)(sorted_cv + NNZ) + 255) & ~(uintptr_t)255);
    size_t need = (size_t)((char*)(cath_us + (size_t)N_CAT * D) - (char*)d_ws);
    int use16 = (ws_size >= need);

    hipMemsetAsync(ccnt, 0, (size_t)NBK * sizeof(int), stream);

    coarse_hist_kernel<<<512, 256, 0, stream>>>(head, imr, ccnt);
    coarse_scan_kernel<<<1, 256, 0, stream>>>(ccnt, cbase_e, cbase_u,
                                              ccur_e, ccur_u, offs_e, offs_u);
    pass1_edges_kernel<<<(NEDGE + T1 - 1) / T1, 256, 0, stream>>>(
        head, tail, etype, ccur_e, sorted_ta);
    pass1_users_kernel<<<(NNZ + T1 - 1) / T1, 256, 0, stream>>>(
        imr, imc, imv, ccur_u, sorted_cv);
    pass2_kernel<<<NBK, 256, 0, stream>>>(cbase_e, cbase_u, offs_e, offs_u,
                                          sorted_ta, sorted_cv);
    // scale = 1 + softmax(U W^T) W  -> uagg (consumed in place by spmm)
    scale_kernel<<<(N_USERS + 255) / 256, 256, 0, stream>>>(uemb, W, uagg);
    if (use16) {
        norm2_kernel<1><<<(N_CAT + 63) / 64, 256, 0, stream>>>(cat, W, norm2, cath_us);
        cat_agg_sorted_kernel<1><<<N_CAT / 4, 256, 0, stream>>>(
            offs_e, sorted_ta, norm2, cat, (const uint4*)cath_us, W, cat_agg);
        spmm_user_kernel<1><<<N_USERS / 4, 256, 0, stream>>>(
            offs_u, sorted_cv, cat, (const uint4*)cath_us, uagg);
    } else {
        norm2_kernel<0><<<(N_CAT + 63) / 64, 256, 0, stream>>>(cat, W, norm2, nullptr);
        cat_agg_sorted_kernel<0><<<N_CAT / 4, 256, 0, stream>>>(
            offs_e, sorted_ta, norm2, cat, nullptr, W, cat_agg);
        spmm_user_kernel<0><<<N_USERS / 4, 256, 0, stream>>>(
            offs_u, sorted_cv, cat, nullptr, uagg);
    }
}

// Round 6
// 353.321 us; speedup vs baseline: 1.3497x; 1.0704x over previous
//
#include <hip/hip_runtime.h>
#include <hip/hip_bf16.h>
#include <hip/hip_fp16.h>
#include <float.h>
#include <stdint.h>

#define N_CAT   100000
#define N_USERS 50000
#define N_REL   32
#define D       64
#define NEDGE   1600000
#define NNZ     1000000

#define EB_SHIFT 9
#define EB_SIZE  512
#define NBKE     ((N_CAT + EB_SIZE - 1) / EB_SIZE)    // 196 edge buckets
#define UB_SHIFT 8
#define UB_SIZE  256
#define NBKU     ((N_USERS + UB_SIZE - 1) / UB_SIZE)  // 196 user buckets
#define NBK      (NBKE + NBKU)                        // 392

#define T1   4096      // pass1 tile (16 recs/thread @ 256 threads)
#define ECAP 15360     // pass2 edge bucket LDS capacity
#define UCAP 7680      // pass2 user bucket LDS capacity

// LDS W row stride in float4 (68 floats): breaks the "every 256B row starts at
// bank 0" 8-way conflict down to <=4-way for grouped ds_read_b128.
#define WSTRIDE 17

// ---------------------------------------------------------------------------
// ws: norm2[N_CAT*32] f32 | ccnt[392] | cbase_e[197] | cbase_u[197] |
//     ccur_e[196] | ccur_u[196] | offs_e[100001] | offs_u[50001] |
//     sorted_ta[NEDGE] int | sorted_cv[NNZ] int2 | cat_f16[N_CAT*64] (aligned)
// scale[u][d] = 1 + (softmax(u.W^T)@W)[d] is precomputed INTO uagg (d_out)
// by scale_kernel; spmm multiplies in place.
// ---------------------------------------------------------------------------

__device__ __forceinline__ unsigned int pack_half2(float a, float b) {
    return (unsigned int)__half_as_ushort(__float2half_rn(a)) |
           ((unsigned int)__half_as_ushort(__float2half_rn(b)) << 16);
}

// Gather one 64-dim row, 8 lanes x 8 dims. F16: one uint4 = one 128B line.
template<int F16>
__device__ __forceinline__ void load_row8(const float4* __restrict__ catv4,
                                          const uint4* __restrict__ cath4,
                                          int row, int gl, float f[8]) {
    if (F16) {
        uint4 h = cath4[(size_t)row * 8 + gl];
        const __half2* hp = (const __half2*)&h;
        float2 a = __half22float2(hp[0]);
        float2 b = __half22float2(hp[1]);
        float2 c = __half22float2(hp[2]);
        float2 d = __half22float2(hp[3]);
        f[0] = a.x; f[1] = a.y; f[2] = b.x; f[3] = b.y;
        f[4] = c.x; f[5] = c.y; f[6] = d.x; f[7] = d.y;
    } else {
        float4 a = catv4[(size_t)row * 16 + gl * 2];
        float4 b = catv4[(size_t)row * 16 + gl * 2 + 1];
        f[0] = a.x; f[1] = a.y; f[2] = a.z; f[3] = a.w;
        f[4] = b.x; f[5] = b.y; f[6] = b.z; f[7] = b.w;
    }
}

// Butterfly reduce-scatter over the 8 groups (7 shfl, HW-validated):
// lane ends with the full sum of dim (lane&7)*8 + brev3(lane>>3).
__device__ __forceinline__ float reduce_scatter8(const float a[8], int lane) {
    int b3 = (lane >> 3) & 1, b4 = (lane >> 4) & 1, b5 = (lane >> 5) & 1;
    float r[4];
#pragma unroll
    for (int j = 0; j < 4; ++j) {
        float x = b3 ? a[j] : a[j + 4];
        float k = b3 ? a[j + 4] : a[j];
        r[j] = k + __shfl_xor(x, 8);
    }
    float s[2];
#pragma unroll
    for (int j = 0; j < 2; ++j) {
        float x = b4 ? r[j] : r[j + 2];
        float k = b4 ? r[j + 2] : r[j];
        s[j] = k + __shfl_xor(x, 16);
    }
    float x = b5 ? s[0] : s[1];
    float k = b5 ? s[1] : s[0];
    return k + __shfl_xor(x, 32);
}

__device__ __forceinline__ int dim_of_lane(int lane) {
    int g = lane >> 3;
    return ((lane & 7) << 3) | ((g & 1) << 2) | (g & 2) | (g >> 2);
}

// norm2[n][r] = sum_d cat[n][d]^2 * W[r][d]^2.
template<int W16>
__global__ __launch_bounds__(256) void norm2_kernel(
        const float* __restrict__ cat,
        const float* __restrict__ W,
        float* __restrict__ norm2,
        unsigned short* __restrict__ cath) {
    __shared__ float4 w2[N_REL * 16];   // squared W, 8 KB
    int t = threadIdx.x;
    const float4* Wv = (const float4*)W;
    for (int i = t; i < N_REL * 16; i += 256) {
        float4 v = Wv[i];
        v.x *= v.x; v.y *= v.y; v.z *= v.z; v.w *= v.w;
        w2[i] = v;
    }
    __syncthreads();

    int node = blockIdx.x * 64 + (t >> 2);
    int q    = t & 3;
    if (node >= N_CAT) return;

    const float4* catv = (const float4*)cat;
    float acc[N_REL];
#pragma unroll
    for (int r = 0; r < N_REL; ++r) acc[r] = 0.f;

    uint2 hp[4];
#pragma unroll
    for (int c = 0; c < 4; ++c) {
        float4 xv = catv[(size_t)node * 16 + q * 4 + c];
        if (W16) {
            hp[c].x = pack_half2(xv.x, xv.y);
            hp[c].y = pack_half2(xv.z, xv.w);
        }
        xv.x *= xv.x; xv.y *= xv.y; xv.z *= xv.z; xv.w *= xv.w;
#pragma unroll
        for (int r = 0; r < N_REL; ++r) {
            float4 wv = w2[r * 16 + q * 4 + c];
            acc[r] += xv.x * wv.x + xv.y * wv.y + xv.z * wv.z + xv.w * wv.w;
        }
    }
    if (W16) {
        uint4* cv16 = (uint4*)cath;
        cv16[(size_t)node * 8 + q * 2]     = make_uint4(hp[0].x, hp[0].y, hp[1].x, hp[1].y);
        cv16[(size_t)node * 8 + q * 2 + 1] = make_uint4(hp[2].x, hp[2].y, hp[3].x, hp[3].y);
    }
#pragma unroll
    for (int r = 0; r < N_REL; ++r) {
        acc[r] += __shfl_xor(acc[r], 1);
        acc[r] += __shfl_xor(acc[r], 2);
    }
    float4* nv = (float4*)norm2;
    size_t base = (size_t)node * 8 + q * 2;
    if (q == 0) {
        nv[base]     = make_float4(acc[0],  acc[1],  acc[2],  acc[3]);
        nv[base + 1] = make_float4(acc[4],  acc[5],  acc[6],  acc[7]);
    } else if (q == 1) {
        nv[base]     = make_float4(acc[8],  acc[9],  acc[10], acc[11]);
        nv[base + 1] = make_float4(acc[12], acc[13], acc[14], acc[15]);
    } else if (q == 2) {
        nv[base]     = make_float4(acc[16], acc[17], acc[18], acc[19]);
        nv[base + 1] = make_float4(acc[20], acc[21], acc[22], acc[23]);
    } else {
        nv[base]     = make_float4(acc[24], acc[25], acc[26], acc[27]);
        nv[base + 1] = make_float4(acc[28], acc[29], acc[30], acc[31]);
    }
}

// per-WG LDS histogram over 392 coarse buckets, single flush
__global__ void coarse_hist_kernel(const int* __restrict__ head,
                                   const int* __restrict__ imr,
                                   int* __restrict__ ccnt) {
    __shared__ int h[NBK];
    int t = threadIdx.x;
    for (int i = t; i < NBK; i += 256) h[i] = 0;
    __syncthreads();
    int stride = gridDim.x * 256;
    for (int i = blockIdx.x * 256 + t; i < NEDGE + NNZ; i += stride) {
        if (i < NEDGE) atomicAdd(&h[head[i] >> EB_SHIFT], 1);
        else           atomicAdd(&h[NBKE + (imr[i - NEDGE] >> UB_SHIFT)], 1);
    }
    __syncthreads();
    for (int i = t; i < NBK; i += 256) if (h[i]) atomicAdd(&ccnt[i], h[i]);
}

// single-WG scan of 392 coarse bins -> bucket bases + cursors + sentinels
__global__ void coarse_scan_kernel(const int* __restrict__ ccnt,
                                   int* __restrict__ cbase_e, int* __restrict__ cbase_u,
                                   int* __restrict__ ccur_e,  int* __restrict__ ccur_u,
                                   int* __restrict__ offs_e,  int* __restrict__ offs_u) {
    __shared__ int sc[256];
    int t = threadIdx.x;
    int c = (t < NBKE) ? ccnt[t] : 0;
    sc[t] = c; __syncthreads();
    for (int off = 1; off < 256; off <<= 1) {
        int v = (t >= off) ? sc[t - off] : 0; __syncthreads();
        sc[t] += v; __syncthreads();
    }
    int excl = sc[t] - c;
    if (t < NBKE) { cbase_e[t] = excl; ccur_e[t] = excl; }
    if (t == NBKE - 1) cbase_e[NBKE] = excl + c;
    __syncthreads();
    c = (t < NBKU) ? ccnt[NBKE + t] : 0;
    sc[t] = c; __syncthreads();
    for (int off = 1; off < 256; off <<= 1) {
        int v = (t >= off) ? sc[t - off] : 0; __syncthreads();
        sc[t] += v; __syncthreads();
    }
    excl = sc[t] - c;
    if (t < NBKU) { cbase_u[t] = excl; ccur_u[t] = excl; }
    if (t == NBKU - 1) cbase_u[NBKU] = excl + c;
    if (t == 0) { offs_e[N_CAT] = NEDGE; offs_u[N_USERS] = NNZ; }
}

// pass1 edges: tile -> LDS count/scan -> ONE global atomic per (tile,bucket)
__global__ __launch_bounds__(256) void pass1_edges_kernel(
        const int* __restrict__ head, const int* __restrict__ tail,
        const int* __restrict__ etype, int* __restrict__ ccur_e,
        int* __restrict__ sorted_ta) {
    __shared__ int cnt[256], loc[256], base[256], sc[256];
    __shared__ int stage[T1];
    __shared__ int gpos[T1];
    int t = threadIdx.x;
    int tile = blockIdx.x * T1;
    cnt[t] = 0;
    __syncthreads();
    int rec[16], bk[16];
#pragma unroll
    for (int k = 0; k < 16; ++k) {
        int i = tile + k * 256 + t;
        if (i < NEDGE) {
            int h = head[i], tl = tail[i], r = etype[i] - 1;
            bk[k]  = h >> EB_SHIFT;
            rec[k] = ((h & (EB_SIZE - 1)) << 22) | (tl << 5) | r;
            atomicAdd(&cnt[bk[k]], 1);
        } else bk[k] = -1;
    }
    __syncthreads();
    int c = cnt[t];
    sc[t] = c; __syncthreads();
    for (int off = 1; off < 256; off <<= 1) {
        int v = (t >= off) ? sc[t - off] : 0; __syncthreads();
        sc[t] += v; __syncthreads();
    }
    loc[t] = sc[t] - c;
    if (t < NBKE && c > 0) base[t] = atomicAdd(&ccur_e[t], c);
    __syncthreads();
    cnt[t] = loc[t];
    __syncthreads();
#pragma unroll
    for (int k = 0; k < 16; ++k) {
        if (bk[k] >= 0) {
            int p = atomicAdd(&cnt[bk[k]], 1);
            stage[p] = rec[k];
            gpos[p]  = base[bk[k]] + (p - loc[bk[k]]);
        }
    }
    __syncthreads();
    int nv = min(T1, NEDGE - tile);
    for (int i = t; i < nv; i += 256) sorted_ta[gpos[i]] = stage[i];
}

__global__ __launch_bounds__(256) void pass1_users_kernel(
        const int* __restrict__ imr, const int* __restrict__ imc,
        const float* __restrict__ imv, int* __restrict__ ccur_u,
        int2* __restrict__ sorted_cv) {
    __shared__ int cnt[256], loc[256], base[256], sc[256];
    __shared__ int2 stage[T1];
    __shared__ int gpos[T1];
    int t = threadIdx.x;
    int tile = blockIdx.x * T1;
    cnt[t] = 0;
    __syncthreads();
    int2 rec[16]; int bk[16];
#pragma unroll
    for (int k = 0; k < 16; ++k) {
        int i = tile + k * 256 + t;
        if (i < NNZ) {
            int rr = imr[i];
            bk[k]  = rr >> UB_SHIFT;
            rec[k] = make_int2(((rr & (UB_SIZE - 1)) << 17) | imc[i],
                               __float_as_int(imv[i]));
            atomicAdd(&cnt[bk[k]], 1);
        } else bk[k] = -1;
    }
    __syncthreads();
    int c = cnt[t];
    sc[t] = c; __syncthreads();
    for (int off = 1; off < 256; off <<= 1) {
        int v = (t >= off) ? sc[t - off] : 0; __syncthreads();
        sc[t] += v; __syncthreads();
    }
    loc[t] = sc[t] - c;
    if (t < NBKU && c > 0) base[t] = atomicAdd(&ccur_u[t], c);
    __syncthreads();
    cnt[t] = loc[t];
    __syncthreads();
#pragma unroll
    for (int k = 0; k < 16; ++k) {
        if (bk[k] >= 0) {
            int p = atomicAdd(&cnt[bk[k]], 1);
            stage[p] = rec[k];
            gpos[p]  = base[bk[k]] + (p - loc[bk[k]]);
        }
    }
    __syncthreads();
    int nv = min(T1, NNZ - tile);
    for (int i = t; i < nv; i += 256) sorted_cv[gpos[i]] = stage[i];
}

// pass2: one WG per coarse bucket; fine counting-sort in LDS; writes fine offs
__global__ __launch_bounds__(256) void pass2_kernel(
        const int* __restrict__ cbase_e, const int* __restrict__ cbase_u,
        int* __restrict__ offs_e, int* __restrict__ offs_u,
        int* __restrict__ sorted_ta, int2* __restrict__ sorted_cv) {
    __shared__ int lds[UCAP * 2];        // 60 KB
    __shared__ int fh[EB_SIZE + 1];
    __shared__ int sc[256];
    int t = threadIdx.x;
    int b = blockIdx.x;
    if (b < NBKE) {
        int h0 = b << EB_SHIFT;
        int start = cbase_e[b], end = cbase_e[b + 1];
        int n = min(end - start, ECAP);
        for (int i = t; i < n; i += 256) lds[i] = sorted_ta[start + i];
        fh[2 * t] = 0; fh[2 * t + 1] = 0;
        __syncthreads();
        for (int i = t; i < n; i += 256) atomicAdd(&fh[lds[i] >> 22], 1);
        __syncthreads();
        int a = fh[2 * t], b2 = fh[2 * t + 1];
        sc[t] = a + b2; __syncthreads();
        for (int off = 1; off < 256; off <<= 1) {
            int v = (t >= off) ? sc[t - off] : 0; __syncthreads();
            sc[t] += v; __syncthreads();
        }
        int pe = sc[t] - (a + b2);
        int lim = min(EB_SIZE, N_CAT - h0);
        if (2 * t     < lim) offs_e[h0 + 2 * t]     = start + pe;
        if (2 * t + 1 < lim) offs_e[h0 + 2 * t + 1] = start + pe + a;
        fh[2 * t] = pe; fh[2 * t + 1] = pe + a;
        __syncthreads();
        for (int i = t; i < n; i += 256) {
            int rec = lds[i];
            int p = atomicAdd(&fh[rec >> 22], 1);
            sorted_ta[start + p] = rec & 0x3FFFFF;     // (tail<<5)|rel
        }
    } else {
        int k = b - NBKE;
        int u0 = k << UB_SHIFT;
        int start = cbase_u[k], end = cbase_u[k + 1];
        int n = min(end - start, UCAP);
        int2* lds2 = (int2*)lds;
        for (int i = t; i < n; i += 256) lds2[i] = sorted_cv[start + i];
        fh[t] = 0;
        __syncthreads();
        for (int i = t; i < n; i += 256) atomicAdd(&fh[lds2[i].x >> 17], 1);
        __syncthreads();
        int c = fh[t];
        sc[t] = c; __syncthreads();
        for (int off = 1; off < 256; off <<= 1) {
            int v = (t >= off) ? sc[t - off] : 0; __syncthreads();
            sc[t] += v; __syncthreads();
        }
        int excl = sc[t] - c;
        int lim = min(UB_SIZE, N_USERS - u0);
        if (t < lim) offs_u[u0 + t] = start + excl;
        fh[t] = excl;
        __syncthreads();
        for (int i = t; i < n; i += 256) {
            int2 rec = lds2[i];
            int p = atomicAdd(&fh[rec.x >> 17], 1);
            sorted_cv[start + p] = make_int2(rec.x & 0x1FFFF, rec.y);
        }
    }
}

#define FMA8(ACC, WS, F, W0, W1)                                         \
    ACC[0] += WS * F[0] * W0.x;  ACC[1] += WS * F[1] * W0.y;             \
    ACC[2] += WS * F[2] * W0.z;  ACC[3] += WS * F[3] * W0.w;             \
    ACC[4] += WS * F[4] * W1.x;  ACC[5] += WS * F[5] * W1.y;             \
    ACC[6] += WS * F[6] * W1.z;  ACC[7] += WS * F[7] * W1.w;

// scale[u][d] = 1 + (softmax(uemb[u]@W^T) @ W)[d], written into uagg.
// One THREAD per user. Round-5 failure: full unroll hoisted 16 float4 loads
// -> 256 VGPR -> spill (78 MB scratch writes, 7% occupancy, 89 us).
// Fix: unroll 1 on the d4 loops (liveness ~50 VGPR: dot[32]+uv+w4) and
// __launch_bounds__(128,6) caps the allocator at ~85 VGPR. All sWt reads
// are wave-uniform broadcasts (free). ~4k VALU ops/thread -> ~5-10 us.
__global__ __launch_bounds__(128, 6) void scale_kernel(
        const float* __restrict__ uemb,
        const float* __restrict__ W,
        float* __restrict__ uagg) {
    __shared__ float sWt[D][N_REL + 4];   // W^T, stride 36 floats (16B-aligned)
    int t = threadIdx.x;
    for (int i = t; i < N_REL * D; i += 128) {
        int r = i >> 6, d = i & 63;
        sWt[d][r] = W[i];
    }
    __syncthreads();
    int u = blockIdx.x * 128 + t;
    if (u >= N_USERS) return;

    const float4* ur4 = (const float4*)(uemb + (size_t)u * D);
    float dot[N_REL];
#pragma unroll
    for (int r = 0; r < N_REL; ++r) dot[r] = 0.f;
#pragma unroll 1
    for (int d4 = 0; d4 < 16; ++d4) {
        float4 uv = ur4[d4];
        float us[4] = {uv.x, uv.y, uv.z, uv.w};
#pragma unroll
        for (int k = 0; k < 4; ++k) {
            const float4* wt4 = (const float4*)sWt[d4 * 4 + k];
#pragma unroll
            for (int r4 = 0; r4 < 8; ++r4) {
                float4 w4 = wt4[r4];
                dot[4 * r4]     += us[k] * w4.x;
                dot[4 * r4 + 1] += us[k] * w4.y;
                dot[4 * r4 + 2] += us[k] * w4.z;
                dot[4 * r4 + 3] += us[k] * w4.w;
            }
        }
    }
    // in-register softmax over 32 rels
    float m = dot[0];
#pragma unroll
    for (int r = 1; r < N_REL; ++r) m = fmaxf(m, dot[r]);
    float s = 0.f;
#pragma unroll
    for (int r = 0; r < N_REL; ++r) { dot[r] = __expf(dot[r] - m); s += dot[r]; }
    float inv = 1.f / s;

    float4* out4 = (float4*)(uagg + (size_t)u * D);
#pragma unroll 1
    for (int d4 = 0; d4 < 16; ++d4) {
        float p[4];
#pragma unroll
        for (int k = 0; k < 4; ++k) {
            const float4* wt4 = (const float4*)sWt[d4 * 4 + k];
            float acc = 0.f;
#pragma unroll
            for (int r4 = 0; r4 < 8; ++r4) {
                float4 w4 = wt4[r4];
                acc += dot[4 * r4] * w4.x + dot[4 * r4 + 1] * w4.y
                     + dot[4 * r4 + 2] * w4.z + dot[4 * r4 + 3] * w4.w;
            }
            p[k] = 1.f + acc * inv;
        }
        out4[d4] = make_float4(p[0], p[1], p[2], p[3]);
    }
}

// one wave per head (round-3 proven body). Output: 7-shfl reduce-scatter +
// wave-private LDS transpose + single coalesced float4 store by 16 lanes.
template<int F16>
__global__ __launch_bounds__(256, 4) void cat_agg_sorted_kernel(
        const int* __restrict__ offs_e,
        const int* __restrict__ sorted_ta,
        const float* __restrict__ norm2,
        const float* __restrict__ cat,
        const uint4* __restrict__ cath4,
        const float* __restrict__ W,
        float* __restrict__ cat_agg) {
    __shared__ float4 sW4[N_REL * WSTRIDE];   // 8704 B
    __shared__ float  scr[4][D];              // 1 KB transpose scratch
    {
        const float4* Wv = (const float4*)W;
        for (int i = threadIdx.x; i < N_REL * 16; i += 256)
            sW4[(i >> 4) * WSTRIDE + (i & 15)] = Wv[i];
    }
    __syncthreads();

    const float4* catv4 = (const float4*)cat;
    int wv   = threadIdx.x >> 6;
    int lane = threadIdx.x & 63;
    int grp  = lane >> 3;
    int gl   = lane & 7;
    int h = blockIdx.x * 4 + wv;
    int start = offs_e[h];
    int end   = offs_e[h + 1];
    int deg   = end - start;

    float accA[8], accB[8];
#pragma unroll
    for (int k = 0; k < 8; ++k) { accA[k] = 0.f; accB[k] = 0.f; }

    if (deg <= 32) {
        int rec = 0;
        if (lane < deg) rec = sorted_ta[start + lane];
        int tt = rec >> 5, r = rec & 31;
        float n2t = norm2[(size_t)tt * N_REL + r];
        float n2h = norm2[(size_t)h  * N_REL + r];

        // prefetch row data NOW (overlaps softmax shfl chain)
        int tA0 = __shfl(rec, grp),      tB0 = __shfl(rec, 8 + grp);
        float fA0[8], fB0[8], fA1[8], fB1[8];
        load_row8<F16>(catv4, cath4, tA0 >> 5, gl, fA0);
        load_row8<F16>(catv4, cath4, tB0 >> 5, gl, fB0);
        int tA1 = 0, tB1 = 0;
        if (deg > 16) {
            tA1 = __shfl(rec, 16 + grp); tB1 = __shfl(rec, 24 + grp);
            load_row8<F16>(catv4, cath4, tA1 >> 5, gl, fA1);
            load_row8<F16>(catv4, cath4, tB1 >> 5, gl, fB1);
        }

        float att = (lane < deg) ? n2h * n2t : -FLT_MAX;
        float m = att;
        m = fmaxf(m, __shfl_xor(m, 1));
        m = fmaxf(m, __shfl_xor(m, 2));
        m = fmaxf(m, __shfl_xor(m, 4));
        m = fmaxf(m, __shfl_xor(m, 8));
        if (deg > 16) m = fmaxf(m, __shfl_xor(m, 16));
        float ex = (lane < deg) ? __expf(att - m) : 0.f;
        float ssum = ex;
        ssum += __shfl_xor(ssum, 1);
        ssum += __shfl_xor(ssum, 2);
        ssum += __shfl_xor(ssum, 4);
        ssum += __shfl_xor(ssum, 8);
        if (deg > 16) ssum += __shfl_xor(ssum, 16);
        float w = (deg > 0) ? ex / ssum : 0.f;

        float wA0 = __shfl(w, grp), wB0 = __shfl(w, 8 + grp);
        const float4* wrA0 = &sW4[(tA0 & 31) * WSTRIDE + gl * 2];
        const float4* wrB0 = &sW4[(tB0 & 31) * WSTRIDE + gl * 2];
        float4 wa00 = wrA0[0], wa01 = wrA0[1];
        float4 wb00 = wrB0[0], wb01 = wrB0[1];
        FMA8(accA, wA0, fA0, wa00, wa01)
        FMA8(accB, wB0, fB0, wb00, wb01)
        if (deg > 16) {
            float wA1 = __shfl(w, 16 + grp), wB1 = __shfl(w, 24 + grp);
            const float4* wrA1 = &sW4[(tA1 & 31) * WSTRIDE + gl * 2];
            const float4* wrB1 = &sW4[(tB1 & 31) * WSTRIDE + gl * 2];
            float4 wa10 = wrA1[0], wa11 = wrA1[1];
            float4 wb10 = wrB1[0], wb11 = wrB1[1];
            FMA8(accA, wA1, fA1, wa10, wa11)
            FMA8(accB, wB1, fB1, wb10, wb11)
        }
    } else if (deg <= 64) {
        int   rec = 0;
        float att = -FLT_MAX;
        if (lane < deg) {
            rec = sorted_ta[start + lane];
            int tt = rec >> 5, r = rec & 31;
            att = norm2[h * N_REL + r] * norm2[(size_t)tt * N_REL + r];
        }
        float m = att;
#pragma unroll
        for (int off = 32; off > 0; off >>= 1) m = fmaxf(m, __shfl_xor(m, off));
        float ex = (lane < deg) ? __expf(att - m) : 0.f;
        float ssum = ex;
#pragma unroll
        for (int off = 32; off > 0; off >>= 1) ssum += __shfl_xor(ssum, off);
        float w = (deg > 0) ? ex / ssum : 0.f;

        for (int e = 0; e < deg; e += 16) {
            int   tA = __shfl(rec, e + grp);
            float wA = __shfl(w,   e + grp);
            int   tB = __shfl(rec, e + 8 + grp);
            float wB = __shfl(w,   e + 8 + grp);
            float fA[8], fB[8];
            load_row8<F16>(catv4, cath4, tA >> 5, gl, fA);
            load_row8<F16>(catv4, cath4, tB >> 5, gl, fB);
            const float4* wrA = &sW4[(tA & 31) * WSTRIDE + gl * 2];
            const float4* wrB = &sW4[(tB & 31) * WSTRIDE + gl * 2];
            float4 wa0 = wrA[0], wa1 = wrA[1];
            float4 wb0 = wrB[0], wb1 = wrB[1];
            FMA8(accA, wA, fA, wa0, wa1)
            FMA8(accB, wB, fB, wb0, wb1)
        }
    } else {
        float m = -FLT_MAX;
        for (int j = lane; j < deg; j += 64) {
            int rec = sorted_ta[start + j];
            int tt = rec >> 5, r = rec & 31;
            m = fmaxf(m, norm2[h * N_REL + r] * norm2[(size_t)tt * N_REL + r]);
        }
#pragma unroll
        for (int off = 32; off > 0; off >>= 1) m = fmaxf(m, __shfl_xor(m, off));
        float ssum = 0.f;
        for (int j = lane; j < deg; j += 64) {
            int rec = sorted_ta[start + j];
            int tt = rec >> 5, r = rec & 31;
            ssum += __expf(norm2[h * N_REL + r] * norm2[(size_t)tt * N_REL + r] - m);
        }
#pragma unroll
        for (int off = 32; off > 0; off >>= 1) ssum += __shfl_xor(ssum, off);
        float inv = 1.f / ssum;
        for (int j0 = 0; j0 < deg; j0 += 64) {
            int n = min(64, deg - j0);
            int   rec = 0;
            float w   = 0.f;
            if (lane < n) {
                rec = sorted_ta[start + j0 + lane];
                int tt = rec >> 5, r = rec & 31;
                w = __expf(norm2[h * N_REL + r] * norm2[(size_t)tt * N_REL + r] - m) * inv;
            }
            for (int e = 0; e < n; e += 16) {
                int   tA = __shfl(rec, e + grp);
                float wA = __shfl(w,   e + grp);
                int   tB = __shfl(rec, e + 8 + grp);
                float wB = __shfl(w,   e + 8 + grp);
                float fA[8], fB[8];
                load_row8<F16>(catv4, cath4, tA >> 5, gl, fA);
                load_row8<F16>(catv4, cath4, tB >> 5, gl, fB);
                const float4* wrA = &sW4[(tA & 31) * WSTRIDE + gl * 2];
                const float4* wrB = &sW4[(tB & 31) * WSTRIDE + gl * 2];
                float4 wa0 = wrA[0], wa1 = wrA[1];
                float4 wb0 = wrB[0], wb1 = wrB[1];
                FMA8(accA, wA, fA, wa0, wa1)
                FMA8(accB, wB, fB, wb0, wb1)
            }
        }
    }

    float a[8];
#pragma unroll
    for (int k = 0; k < 8; ++k) a[k] = accA[k] + accB[k];
    float tot = reduce_scatter8(a, lane);
    scr[wv][dim_of_lane(lane)] = tot;         // 2-way bank alias: free
    // wave-private exchange: in-wave LDS ops are ordered; no barrier needed
    if (lane < 16) {
        float4 o = ((const float4*)scr[wv])[lane];
        ((float4*)&cat_agg[(size_t)h * D])[lane] = o;
    }
}

// spmm: gather + reduce-scatter only; epilogue is one coalesced multiply by
// the precomputed scale (read from uagg in place). ~17 DS ops/wave.
template<int F16>
__global__ __launch_bounds__(256, 4) void spmm_user_kernel(
        const int* __restrict__ offs_u,
        const int2* __restrict__ sorted_cv,
        const float* __restrict__ cat,
        const uint4* __restrict__ cath4,
        float* __restrict__ uagg) {
    __shared__ float scr[4][D];               // 1 KB
    const float4* catv4 = (const float4*)cat;
    int wv   = threadIdx.x >> 6;
    int lane = threadIdx.x & 63;
    int grp  = lane >> 3;
    int gl   = lane & 7;
    int u = blockIdx.x * 4 + wv;
    int start = offs_u[u];
    int end   = offs_u[u + 1];
    int deg   = end - start;

    float accA[8], accB[8];
#pragma unroll
    for (int k = 0; k < 8; ++k) { accA[k] = 0.f; accB[k] = 0.f; }

    if (deg <= 32) {
        int my_c = 0; float my_v = 0.f;
        if (lane < deg) {
            int2 cv = sorted_cv[start + lane];
            my_c = cv.x;
            my_v = __int_as_float(cv.y);
        }
        int   cA0 = __shfl(my_c, grp),     cB0 = __shfl(my_c, 8 + grp);
        float vA0 = __shfl(my_v, grp),     vB0 = __shfl(my_v, 8 + grp);
        float fA0[8], fB0[8], fA1[8], fB1[8];
        load_row8<F16>(catv4, cath4, cA0, gl, fA0);
        load_row8<F16>(catv4, cath4, cB0, gl, fB0);
        float vA1 = 0.f, vB1 = 0.f;
        if (deg > 16) {
            int cA1 = __shfl(my_c, 16 + grp), cB1 = __shfl(my_c, 24 + grp);
            vA1 = __shfl(my_v, 16 + grp); vB1 = __shfl(my_v, 24 + grp);
            load_row8<F16>(catv4, cath4, cA1, gl, fA1);
            load_row8<F16>(catv4, cath4, cB1, gl, fB1);
#pragma unroll
            for (int k = 0; k < 8; ++k) {
                accA[k] += vA1 * fA1[k];
                accB[k] += vB1 * fB1[k];
            }
        }
#pragma unroll
        for (int k = 0; k < 8; ++k) {
            accA[k] += vA0 * fA0[k];
            accB[k] += vB0 * fB0[k];
        }
    } else {
        for (int j0 = 0; j0 < deg; j0 += 64) {
            int n = min(64, deg - j0);
            int   my_c = 0;
            float my_v = 0.f;
            if (lane < n) {
                int2 cv = sorted_cv[start + j0 + lane];
                my_c = cv.x;
                my_v = __int_as_float(cv.y);
            }
            for (int e = 0; e < n; e += 16) {
                int   cA = __shfl(my_c, e + grp);
                float vA = __shfl(my_v, e + grp);
                int   cB = __shfl(my_c, e + 8 + grp);
                float vB = __shfl(my_v, e + 8 + grp);
                float fA[8], fB[8];
                load_row8<F16>(catv4, cath4, cA, gl, fA);
                load_row8<F16>(catv4, cath4, cB, gl, fB);
#pragma unroll
                for (int k = 0; k < 8; ++k) {
                    accA[k] += vA * fA[k];
                    accB[k] += vB * fB[k];
                }
            }
        }
    }

    float a[8];
#pragma unroll
    for (int k = 0; k < 8; ++k) a[k] = accA[k] + accB[k];
    float tot = reduce_scatter8(a, lane);
    scr[wv][dim_of_lane(lane)] = tot;
    if (lane < 16) {
        float4 o = ((const float4*)scr[wv])[lane];
        float4* row = (float4*)&uagg[(size_t)u * D];
        float4 s = row[lane];                 // scale = 1 + proj (precomputed)
        row[lane] = make_float4(o.x * s.x, o.y * s.y, o.z * s.z, o.w * s.w);
    }
}

extern "C" void kernel_launch(void* const* d_in, const int* in_sizes, int n_in,
                              void* d_out, int out_size, void* d_ws, size_t ws_size,
                              hipStream_t stream) {
    const float* cat   = (const float*)d_in[0];
    const float* uemb  = (const float*)d_in[1];
    const int*   eidx  = (const int*)d_in[2];
    const int*   etype = (const int*)d_in[3];
    const int*   imr   = (const int*)d_in[4];
    const int*   imc   = (const int*)d_in[5];
    const float* imv   = (const float*)d_in[6];
    const float* W     = (const float*)d_in[7];
    const int* head = eidx;
    const int* tail = eidx + NEDGE;

    float* out     = (float*)d_out;
    float* cat_agg = out;                         // [N_CAT, D]
    float* uagg    = out + (size_t)N_CAT * D;     // [N_USERS, D]

    float* norm2   = (float*)d_ws;
    int*   ccnt    = (int*)(norm2 + (size_t)N_CAT * N_REL);
    int*   cbase_e = ccnt + NBK;
    int*   cbase_u = cbase_e + NBKE + 1;
    int*   ccur_e  = cbase_u + NBKU + 1;
    int*   ccur_u  = ccur_e + NBKE;
    int*   offs_e  = ccur_u + NBKU;
    int*   offs_u  = offs_e + N_CAT + 1;
    int*   sorted_ta = offs_u + N_USERS + 1;
    int2*  sorted_cv = (int2*)(sorted_ta + NEDGE);

    unsigned short* cath_us =
        (unsigned short*)(((uintptr_t)(sorted_cv + NNZ) + 255) & ~(uintptr_t)255);
    size_t need = (size_t)((char*)(cath_us + (size_t)N_CAT * D) - (char*)d_ws);
    int use16 = (ws_size >= need);

    hipMemsetAsync(ccnt, 0, (size_t)NBK * sizeof(int), stream);

    coarse_hist_kernel<<<512, 256, 0, stream>>>(head, imr, ccnt);
    coarse_scan_kernel<<<1, 256, 0, stream>>>(ccnt, cbase_e, cbase_u,
                                              ccur_e, ccur_u, offs_e, offs_u);
    pass1_edges_kernel<<<(NEDGE + T1 - 1) / T1, 256, 0, stream>>>(
        head, tail, etype, ccur_e, sorted_ta);
    pass1_users_kernel<<<(NNZ + T1 - 1) / T1, 256, 0, stream>>>(
        imr, imc, imv, ccur_u, sorted_cv);
    pass2_kernel<<<NBK, 256, 0, stream>>>(cbase_e, cbase_u, offs_e, offs_u,
                                          sorted_ta, sorted_cv);
    // scale = 1 + softmax(U W^T) W  -> uagg (consumed in place by spmm)
    scale_kernel<<<(N_USERS + 127) / 128, 128, 0, stream>>>(uemb, W, uagg);
    if (use16) {
        norm2_kernel<1><<<(N_CAT + 63) / 64, 256, 0, stream>>>(cat, W, norm2, cath_us);
        cat_agg_sorted_kernel<1><<<N_CAT / 4, 256, 0, stream>>>(
            offs_e, sorted_ta, norm2, cat, (const uint4*)cath_us, W, cat_agg);
        spmm_user_kernel<1><<<N_USERS / 4, 256, 0, stream>>>(
            offs_u, sorted_cv, cat, (const uint4*)cath_us, uagg);
    } else {
        norm2_kernel<0><<<(N_CAT + 63) / 64, 256, 0, stream>>>(cat, W, norm2, nullptr);
        cat_agg_sorted_kernel<0><<<N_CAT / 4, 256, 0, stream>>>(
            offs_e, sorted_ta, norm2, cat, nullptr, W, cat_agg);
        spmm_user_kernel<0><<<N_USERS / 4, 256, 0, stream>>>(
            offs_u, sorted_cv, cat, nullptr, uagg);
    }
}

// Round 7
// 309.805 us; speedup vs baseline: 1.5392x; 1.1405x over previous
//
#include <hip/hip_runtime.h>
#include <hip/hip_bf16.h>
#include <hip/hip_fp16.h>
#include <float.h>
#include <stdint.h>

#define N_CAT   100000
#define N_USERS 50000
#define N_REL   32
#define D       64
#define NEDGE   1600000
#define NNZ     1000000

#define EB_SHIFT 9
#define EB_SIZE  512
#define NBKE     ((N_CAT + EB_SIZE - 1) / EB_SIZE)    // 196 edge buckets
#define UB_SHIFT 8
#define UB_SIZE  256
#define NBKU     ((N_USERS + UB_SIZE - 1) / UB_SIZE)  // 196 user buckets
#define NBK      (NBKE + NBKU)                        // 392

#define T1   4096      // pass1 tile (16 recs/thread @ 256 threads)
#define ECAP 15360     // pass2 edge bucket LDS capacity
#define UCAP 7680      // pass2 user bucket LDS capacity

// LDS W row stride in float4 (68 floats): breaks the "every 256B row starts at
// bank 0" 8-way conflict down to <=4-way for grouped ds_read_b128.
#define WSTRIDE 17

// ---------------------------------------------------------------------------
// ws: norm2[N_CAT*32] f32 | ccnt[392] | cbase_e[197] | cbase_u[197] |
//     ccur_e[196] | ccur_u[196] | offs_e[100001] | offs_u[50001] |
//     sorted_ta[NEDGE] int | sorted_cv[NNZ] int2 | cat_f16[N_CAT*64] (aligned)
// scale[u][d] = 1 + (softmax(u.W^T)@W)[d] is precomputed INTO uagg (d_out)
// by scale_kernel; spmm multiplies in place.
// ---------------------------------------------------------------------------

__device__ __forceinline__ unsigned int pack_half2(float a, float b) {
    return (unsigned int)__half_as_ushort(__float2half_rn(a)) |
           ((unsigned int)__half_as_ushort(__float2half_rn(b)) << 16);
}

// Gather one 64-dim row, 8 lanes x 8 dims. F16: one uint4 = one 128B line.
template<int F16>
__device__ __forceinline__ void load_row8(const float4* __restrict__ catv4,
                                          const uint4* __restrict__ cath4,
                                          int row, int gl, float f[8]) {
    if (F16) {
        uint4 h = cath4[(size_t)row * 8 + gl];
        const __half2* hp = (const __half2*)&h;
        float2 a = __half22float2(hp[0]);
        float2 b = __half22float2(hp[1]);
        float2 c = __half22float2(hp[2]);
        float2 d = __half22float2(hp[3]);
        f[0] = a.x; f[1] = a.y; f[2] = b.x; f[3] = b.y;
        f[4] = c.x; f[5] = c.y; f[6] = d.x; f[7] = d.y;
    } else {
        float4 a = catv4[(size_t)row * 16 + gl * 2];
        float4 b = catv4[(size_t)row * 16 + gl * 2 + 1];
        f[0] = a.x; f[1] = a.y; f[2] = a.z; f[3] = a.w;
        f[4] = b.x; f[5] = b.y; f[6] = b.z; f[7] = b.w;
    }
}

// Butterfly reduce-scatter over the 8 groups (7 shfl, HW-validated):
// lane ends with the full sum of dim (lane&7)*8 + brev3(lane>>3).
__device__ __forceinline__ float reduce_scatter8(const float a[8], int lane) {
    int b3 = (lane >> 3) & 1, b4 = (lane >> 4) & 1, b5 = (lane >> 5) & 1;
    float r[4];
#pragma unroll
    for (int j = 0; j < 4; ++j) {
        float x = b3 ? a[j] : a[j + 4];
        float k = b3 ? a[j + 4] : a[j];
        r[j] = k + __shfl_xor(x, 8);
    }
    float s[2];
#pragma unroll
    for (int j = 0; j < 2; ++j) {
        float x = b4 ? r[j] : r[j + 2];
        float k = b4 ? r[j + 2] : r[j];
        s[j] = k + __shfl_xor(x, 16);
    }
    float x = b5 ? s[0] : s[1];
    float k = b5 ? s[1] : s[0];
    return k + __shfl_xor(x, 32);
}

__device__ __forceinline__ int dim_of_lane(int lane) {
    int g = lane >> 3;
    return ((lane & 7) << 3) | ((g & 1) << 2) | (g & 2) | (g >> 2);
}

// norm2[n][r] = sum_d cat[n][d]^2 * W[r][d]^2.
template<int W16>
__global__ __launch_bounds__(256) void norm2_kernel(
        const float* __restrict__ cat,
        const float* __restrict__ W,
        float* __restrict__ norm2,
        unsigned short* __restrict__ cath) {
    __shared__ float4 w2[N_REL * 16];   // squared W, 8 KB
    int t = threadIdx.x;
    const float4* Wv = (const float4*)W;
    for (int i = t; i < N_REL * 16; i += 256) {
        float4 v = Wv[i];
        v.x *= v.x; v.y *= v.y; v.z *= v.z; v.w *= v.w;
        w2[i] = v;
    }
    __syncthreads();

    int node = blockIdx.x * 64 + (t >> 2);
    int q    = t & 3;
    if (node >= N_CAT) return;

    const float4* catv = (const float4*)cat;
    float acc[N_REL];
#pragma unroll
    for (int r = 0; r < N_REL; ++r) acc[r] = 0.f;

    uint2 hp[4];
#pragma unroll
    for (int c = 0; c < 4; ++c) {
        float4 xv = catv[(size_t)node * 16 + q * 4 + c];
        if (W16) {
            hp[c].x = pack_half2(xv.x, xv.y);
            hp[c].y = pack_half2(xv.z, xv.w);
        }
        xv.x *= xv.x; xv.y *= xv.y; xv.z *= xv.z; xv.w *= xv.w;
#pragma unroll
        for (int r = 0; r < N_REL; ++r) {
            float4 wv = w2[r * 16 + q * 4 + c];
            acc[r] += xv.x * wv.x + xv.y * wv.y + xv.z * wv.z + xv.w * wv.w;
        }
    }
    if (W16) {
        uint4* cv16 = (uint4*)cath;
        cv16[(size_t)node * 8 + q * 2]     = make_uint4(hp[0].x, hp[0].y, hp[1].x, hp[1].y);
        cv16[(size_t)node * 8 + q * 2 + 1] = make_uint4(hp[2].x, hp[2].y, hp[3].x, hp[3].y);
    }
#pragma unroll
    for (int r = 0; r < N_REL; ++r) {
        acc[r] += __shfl_xor(acc[r], 1);
        acc[r] += __shfl_xor(acc[r], 2);
    }
    float4* nv = (float4*)norm2;
    size_t base = (size_t)node * 8 + q * 2;
    if (q == 0) {
        nv[base]     = make_float4(acc[0],  acc[1],  acc[2],  acc[3]);
        nv[base + 1] = make_float4(acc[4],  acc[5],  acc[6],  acc[7]);
    } else if (q == 1) {
        nv[base]     = make_float4(acc[8],  acc[9],  acc[10], acc[11]);
        nv[base + 1] = make_float4(acc[12], acc[13], acc[14], acc[15]);
    } else if (q == 2) {
        nv[base]     = make_float4(acc[16], acc[17], acc[18], acc[19]);
        nv[base + 1] = make_float4(acc[20], acc[21], acc[22], acc[23]);
    } else {
        nv[base]     = make_float4(acc[24], acc[25], acc[26], acc[27]);
        nv[base + 1] = make_float4(acc[28], acc[29], acc[30], acc[31]);
    }
}

// per-WG LDS histogram over 392 coarse buckets, single flush
__global__ void coarse_hist_kernel(const int* __restrict__ head,
                                   const int* __restrict__ imr,
                                   int* __restrict__ ccnt) {
    __shared__ int h[NBK];
    int t = threadIdx.x;
    for (int i = t; i < NBK; i += 256) h[i] = 0;
    __syncthreads();
    int stride = gridDim.x * 256;
    for (int i = blockIdx.x * 256 + t; i < NEDGE + NNZ; i += stride) {
        if (i < NEDGE) atomicAdd(&h[head[i] >> EB_SHIFT], 1);
        else           atomicAdd(&h[NBKE + (imr[i - NEDGE] >> UB_SHIFT)], 1);
    }
    __syncthreads();
    for (int i = t; i < NBK; i += 256) if (h[i]) atomicAdd(&ccnt[i], h[i]);
}

// single-WG scan of 392 coarse bins -> bucket bases + cursors + sentinels
__global__ void coarse_scan_kernel(const int* __restrict__ ccnt,
                                   int* __restrict__ cbase_e, int* __restrict__ cbase_u,
                                   int* __restrict__ ccur_e,  int* __restrict__ ccur_u,
                                   int* __restrict__ offs_e,  int* __restrict__ offs_u) {
    __shared__ int sc[256];
    int t = threadIdx.x;
    int c = (t < NBKE) ? ccnt[t] : 0;
    sc[t] = c; __syncthreads();
    for (int off = 1; off < 256; off <<= 1) {
        int v = (t >= off) ? sc[t - off] : 0; __syncthreads();
        sc[t] += v; __syncthreads();
    }
    int excl = sc[t] - c;
    if (t < NBKE) { cbase_e[t] = excl; ccur_e[t] = excl; }
    if (t == NBKE - 1) cbase_e[NBKE] = excl + c;
    __syncthreads();
    c = (t < NBKU) ? ccnt[NBKE + t] : 0;
    sc[t] = c; __syncthreads();
    for (int off = 1; off < 256; off <<= 1) {
        int v = (t >= off) ? sc[t - off] : 0; __syncthreads();
        sc[t] += v; __syncthreads();
    }
    excl = sc[t] - c;
    if (t < NBKU) { cbase_u[t] = excl; ccur_u[t] = excl; }
    if (t == NBKU - 1) cbase_u[NBKU] = excl + c;
    if (t == 0) { offs_e[N_CAT] = NEDGE; offs_u[N_USERS] = NNZ; }
}

// pass1 edges: tile -> LDS count/scan -> ONE global atomic per (tile,bucket)
__global__ __launch_bounds__(256) void pass1_edges_kernel(
        const int* __restrict__ head, const int* __restrict__ tail,
        const int* __restrict__ etype, int* __restrict__ ccur_e,
        int* __restrict__ sorted_ta) {
    __shared__ int cnt[256], loc[256], base[256], sc[256];
    __shared__ int stage[T1];
    __shared__ int gpos[T1];
    int t = threadIdx.x;
    int tile = blockIdx.x * T1;
    cnt[t] = 0;
    __syncthreads();
    int rec[16], bk[16];
#pragma unroll
    for (int k = 0; k < 16; ++k) {
        int i = tile + k * 256 + t;
        if (i < NEDGE) {
            int h = head[i], tl = tail[i], r = etype[i] - 1;
            bk[k]  = h >> EB_SHIFT;
            rec[k] = ((h & (EB_SIZE - 1)) << 22) | (tl << 5) | r;
            atomicAdd(&cnt[bk[k]], 1);
        } else bk[k] = -1;
    }
    __syncthreads();
    int c = cnt[t];
    sc[t] = c; __syncthreads();
    for (int off = 1; off < 256; off <<= 1) {
        int v = (t >= off) ? sc[t - off] : 0; __syncthreads();
        sc[t] += v; __syncthreads();
    }
    loc[t] = sc[t] - c;
    if (t < NBKE && c > 0) base[t] = atomicAdd(&ccur_e[t], c);
    __syncthreads();
    cnt[t] = loc[t];
    __syncthreads();
#pragma unroll
    for (int k = 0; k < 16; ++k) {
        if (bk[k] >= 0) {
            int p = atomicAdd(&cnt[bk[k]], 1);
            stage[p] = rec[k];
            gpos[p]  = base[bk[k]] + (p - loc[bk[k]]);
        }
    }
    __syncthreads();
    int nv = min(T1, NEDGE - tile);
    for (int i = t; i < nv; i += 256) sorted_ta[gpos[i]] = stage[i];
}

__global__ __launch_bounds__(256) void pass1_users_kernel(
        const int* __restrict__ imr, const int* __restrict__ imc,
        const float* __restrict__ imv, int* __restrict__ ccur_u,
        int2* __restrict__ sorted_cv) {
    __shared__ int cnt[256], loc[256], base[256], sc[256];
    __shared__ int2 stage[T1];
    __shared__ int gpos[T1];
    int t = threadIdx.x;
    int tile = blockIdx.x * T1;
    cnt[t] = 0;
    __syncthreads();
    int2 rec[16]; int bk[16];
#pragma unroll
    for (int k = 0; k < 16; ++k) {
        int i = tile + k * 256 + t;
        if (i < NNZ) {
            int rr = imr[i];
            bk[k]  = rr >> UB_SHIFT;
            rec[k] = make_int2(((rr & (UB_SIZE - 1)) << 17) | imc[i],
                               __float_as_int(imv[i]));
            atomicAdd(&cnt[bk[k]], 1);
        } else bk[k] = -1;
    }
    __syncthreads();
    int c = cnt[t];
    sc[t] = c; __syncthreads();
    for (int off = 1; off < 256; off <<= 1) {
        int v = (t >= off) ? sc[t - off] : 0; __syncthreads();
        sc[t] += v; __syncthreads();
    }
    loc[t] = sc[t] - c;
    if (t < NBKU && c > 0) base[t] = atomicAdd(&ccur_u[t], c);
    __syncthreads();
    cnt[t] = loc[t];
    __syncthreads();
#pragma unroll
    for (int k = 0; k < 16; ++k) {
        if (bk[k] >= 0) {
            int p = atomicAdd(&cnt[bk[k]], 1);
            stage[p] = rec[k];
            gpos[p]  = base[bk[k]] + (p - loc[bk[k]]);
        }
    }
    __syncthreads();
    int nv = min(T1, NNZ - tile);
    for (int i = t; i < nv; i += 256) sorted_cv[gpos[i]] = stage[i];
}

// pass2: one WG per coarse bucket; fine counting-sort in LDS; writes fine offs
__global__ __launch_bounds__(256) void pass2_kernel(
        const int* __restrict__ cbase_e, const int* __restrict__ cbase_u,
        int* __restrict__ offs_e, int* __restrict__ offs_u,
        int* __restrict__ sorted_ta, int2* __restrict__ sorted_cv) {
    __shared__ int lds[UCAP * 2];        // 60 KB
    __shared__ int fh[EB_SIZE + 1];
    __shared__ int sc[256];
    int t = threadIdx.x;
    int b = blockIdx.x;
    if (b < NBKE) {
        int h0 = b << EB_SHIFT;
        int start = cbase_e[b], end = cbase_e[b + 1];
        int n = min(end - start, ECAP);
        for (int i = t; i < n; i += 256) lds[i] = sorted_ta[start + i];
        fh[2 * t] = 0; fh[2 * t + 1] = 0;
        __syncthreads();
        for (int i = t; i < n; i += 256) atomicAdd(&fh[lds[i] >> 22], 1);
        __syncthreads();
        int a = fh[2 * t], b2 = fh[2 * t + 1];
        sc[t] = a + b2; __syncthreads();
        for (int off = 1; off < 256; off <<= 1) {
            int v = (t >= off) ? sc[t - off] : 0; __syncthreads();
            sc[t] += v; __syncthreads();
        }
        int pe = sc[t] - (a + b2);
        int lim = min(EB_SIZE, N_CAT - h0);
        if (2 * t     < lim) offs_e[h0 + 2 * t]     = start + pe;
        if (2 * t + 1 < lim) offs_e[h0 + 2 * t + 1] = start + pe + a;
        fh[2 * t] = pe; fh[2 * t + 1] = pe + a;
        __syncthreads();
        for (int i = t; i < n; i += 256) {
            int rec = lds[i];
            int p = atomicAdd(&fh[rec >> 22], 1);
            sorted_ta[start + p] = rec & 0x3FFFFF;     // (tail<<5)|rel
        }
    } else {
        int k = b - NBKE;
        int u0 = k << UB_SHIFT;
        int start = cbase_u[k], end = cbase_u[k + 1];
        int n = min(end - start, UCAP);
        int2* lds2 = (int2*)lds;
        for (int i = t; i < n; i += 256) lds2[i] = sorted_cv[start + i];
        fh[t] = 0;
        __syncthreads();
        for (int i = t; i < n; i += 256) atomicAdd(&fh[lds2[i].x >> 17], 1);
        __syncthreads();
        int c = fh[t];
        sc[t] = c; __syncthreads();
        for (int off = 1; off < 256; off <<= 1) {
            int v = (t >= off) ? sc[t - off] : 0; __syncthreads();
            sc[t] += v; __syncthreads();
        }
        int excl = sc[t] - c;
        int lim = min(UB_SIZE, N_USERS - u0);
        if (t < lim) offs_u[u0 + t] = start + excl;
        fh[t] = excl;
        __syncthreads();
        for (int i = t; i < n; i += 256) {
            int2 rec = lds2[i];
            int p = atomicAdd(&fh[rec.x >> 17], 1);
            sorted_cv[start + p] = make_int2(rec.x & 0x1FFFF, rec.y);
        }
    }
}

#define FMA8(ACC, WS, F, W0, W1)                                         \
    ACC[0] += WS * F[0] * W0.x;  ACC[1] += WS * F[1] * W0.y;             \
    ACC[2] += WS * F[2] * W0.z;  ACC[3] += WS * F[3] * W0.w;             \
    ACC[4] += WS * F[4] * W1.x;  ACC[5] += WS * F[5] * W1.y;             \
    ACC[6] += WS * F[6] * W1.z;  ACC[7] += WS * F[7] * W1.w;

// scale[u][d] = 1 + (softmax(uemb[u]@W^T) @ W)[d], written into uagg.
// norm2_kernel's proven decomposition: 4 threads/user (16 dims each),
// 64 users/block -> 782 blocks x 4 waves = 3128 waves (12/CU) vs round-6's
// 782 waves total (7% occupancy, 68 us). Quad butterfly gives each thread
// all 32 dots; softmax in-register; each thread emits 16 dims laid out so
// each store instr is a contiguous 64B sector per user (lanes 0-3 write
// out4[c*4+q]). Liveness ~60 VGPR (acc[32]+few) -> no spill.
__global__ __launch_bounds__(256) void scale_kernel(
        const float* __restrict__ uemb,
        const float* __restrict__ W,
        float* __restrict__ uagg) {
    __shared__ float4 sW[N_REL * 16];   // 8 KB, W row-major float4
    int t = threadIdx.x;
    const float4* Wv = (const float4*)W;
    for (int i = t; i < N_REL * 16; i += 256) sW[i] = Wv[i];
    __syncthreads();

    int u = blockIdx.x * 64 + (t >> 2);
    int q = t & 3;
    if (u >= N_USERS) return;

    const float4* ur4 = (const float4*)(uemb + (size_t)u * D);
    float acc[N_REL];
#pragma unroll
    for (int r = 0; r < N_REL; ++r) acc[r] = 0.f;

#pragma unroll 1
    for (int c = 0; c < 4; ++c) {
        float4 uv = ur4[q * 4 + c];
#pragma unroll 4
        for (int r = 0; r < N_REL; ++r) {
            float4 w4 = sW[r * 16 + q * 4 + c];   // 2-way bank alias: free
            acc[r] += uv.x * w4.x + uv.y * w4.y + uv.z * w4.z + uv.w * w4.w;
        }
    }
    // quad butterfly: all 4 threads of this user get the full 32 dots
#pragma unroll
    for (int r = 0; r < N_REL; ++r) {
        acc[r] += __shfl_xor(acc[r], 1);
        acc[r] += __shfl_xor(acc[r], 2);
    }
    float m = acc[0];
#pragma unroll
    for (int r = 1; r < N_REL; ++r) m = fmaxf(m, acc[r]);
    float s = 0.f;
#pragma unroll
    for (int r = 0; r < N_REL; ++r) { acc[r] = __expf(acc[r] - m); s += acc[r]; }
    float inv = 1.f / s;

    float4* out4 = (float4*)(uagg + (size_t)u * D);
#pragma unroll 1
    for (int c = 0; c < 4; ++c) {
        float px = 0.f, py = 0.f, pz = 0.f, pw = 0.f;
#pragma unroll 4
        for (int r = 0; r < N_REL; ++r) {
            float4 w4 = sW[r * 16 + c * 4 + q];   // lanes 0-3 adjacent: no conflict
            px += acc[r] * w4.x; py += acc[r] * w4.y;
            pz += acc[r] * w4.z; pw += acc[r] * w4.w;
        }
        // lanes 0-3 of a user write out4[c*4 + 0..3]: contiguous 64B sector
        out4[c * 4 + q] = make_float4(1.f + px * inv, 1.f + py * inv,
                                      1.f + pz * inv, 1.f + pw * inv);
    }
}

// one wave per head (round-3 proven body). Output: 7-shfl reduce-scatter +
// wave-private LDS transpose + single coalesced float4 store by 16 lanes.
template<int F16>
__global__ __launch_bounds__(256, 4) void cat_agg_sorted_kernel(
        const int* __restrict__ offs_e,
        const int* __restrict__ sorted_ta,
        const float* __restrict__ norm2,
        const float* __restrict__ cat,
        const uint4* __restrict__ cath4,
        const float* __restrict__ W,
        float* __restrict__ cat_agg) {
    __shared__ float4 sW4[N_REL * WSTRIDE];   // 8704 B
    __shared__ float  scr[4][D];              // 1 KB transpose scratch
    {
        const float4* Wv = (const float4*)W;
        for (int i = threadIdx.x; i < N_REL * 16; i += 256)
            sW4[(i >> 4) * WSTRIDE + (i & 15)] = Wv[i];
    }
    __syncthreads();

    const float4* catv4 = (const float4*)cat;
    int wv   = threadIdx.x >> 6;
    int lane = threadIdx.x & 63;
    int grp  = lane >> 3;
    int gl   = lane & 7;
    int h = blockIdx.x * 4 + wv;
    int start = offs_e[h];
    int end   = offs_e[h + 1];
    int deg   = end - start;

    float accA[8], accB[8];
#pragma unroll
    for (int k = 0; k < 8; ++k) { accA[k] = 0.f; accB[k] = 0.f; }

    if (deg <= 32) {
        int rec = 0;
        if (lane < deg) rec = sorted_ta[start + lane];
        int tt = rec >> 5, r = rec & 31;
        float n2t = norm2[(size_t)tt * N_REL + r];
        float n2h = norm2[(size_t)h  * N_REL + r];

        // prefetch row data NOW (overlaps softmax shfl chain)
        int tA0 = __shfl(rec, grp),      tB0 = __shfl(rec, 8 + grp);
        float fA0[8], fB0[8], fA1[8], fB1[8];
        load_row8<F16>(catv4, cath4, tA0 >> 5, gl, fA0);
        load_row8<F16>(catv4, cath4, tB0 >> 5, gl, fB0);
        int tA1 = 0, tB1 = 0;
        if (deg > 16) {
            tA1 = __shfl(rec, 16 + grp); tB1 = __shfl(rec, 24 + grp);
            load_row8<F16>(catv4, cath4, tA1 >> 5, gl, fA1);
            load_row8<F16>(catv4, cath4, tB1 >> 5, gl, fB1);
        }

        float att = (lane < deg) ? n2h * n2t : -FLT_MAX;
        float m = att;
        m = fmaxf(m, __shfl_xor(m, 1));
        m = fmaxf(m, __shfl_xor(m, 2));
        m = fmaxf(m, __shfl_xor(m, 4));
        m = fmaxf(m, __shfl_xor(m, 8));
        if (deg > 16) m = fmaxf(m, __shfl_xor(m, 16));
        float ex = (lane < deg) ? __expf(att - m) : 0.f;
        float ssum = ex;
        ssum += __shfl_xor(ssum, 1);
        ssum += __shfl_xor(ssum, 2);
        ssum += __shfl_xor(ssum, 4);
        ssum += __shfl_xor(ssum, 8);
        if (deg > 16) ssum += __shfl_xor(ssum, 16);
        float w = (deg > 0) ? ex / ssum : 0.f;

        float wA0 = __shfl(w, grp), wB0 = __shfl(w, 8 + grp);
        const float4* wrA0 = &sW4[(tA0 & 31) * WSTRIDE + gl * 2];
        const float4* wrB0 = &sW4[(tB0 & 31) * WSTRIDE + gl * 2];
        float4 wa00 = wrA0[0], wa01 = wrA0[1];
        float4 wb00 = wrB0[0], wb01 = wrB0[1];
        FMA8(accA, wA0, fA0, wa00, wa01)
        FMA8(accB, wB0, fB0, wb00, wb01)
        if (deg > 16) {
            float wA1 = __shfl(w, 16 + grp), wB1 = __shfl(w, 24 + grp);
            const float4* wrA1 = &sW4[(tA1 & 31) * WSTRIDE + gl * 2];
            const float4* wrB1 = &sW4[(tB1 & 31) * WSTRIDE + gl * 2];
            float4 wa10 = wrA1[0], wa11 = wrA1[1];
            float4 wb10 = wrB1[0], wb11 = wrB1[1];
            FMA8(accA, wA1, fA1, wa10, wa11)
            FMA8(accB, wB1, fB1, wb10, wb11)
        }
    } else if (deg <= 64) {
        int   rec = 0;
        float att = -FLT_MAX;
        if (lane < deg) {
            rec = sorted_ta[start + lane];
            int tt = rec >> 5, r = rec & 31;
            att = norm2[h * N_REL + r] * norm2[(size_t)tt * N_REL + r];
        }
        float m = att;
#pragma unroll
        for (int off = 32; off > 0; off >>= 1) m = fmaxf(m, __shfl_xor(m, off));
        float ex = (lane < deg) ? __expf(att - m) : 0.f;
        float ssum = ex;
#pragma unroll
        for (int off = 32; off > 0; off >>= 1) ssum += __shfl_xor(ssum, off);
        float w = (deg > 0) ? ex / ssum : 0.f;

        for (int e = 0; e < deg; e += 16) {
            int   tA = __shfl(rec, e + grp);
            float wA = __shfl(w,   e + grp);
            int   tB = __shfl(rec, e + 8 + grp);
            float wB = __shfl(w,   e + 8 + grp);
            float fA[8], fB[8];
            load_row8<F16>(catv4, cath4, tA >> 5, gl, fA);
            load_row8<F16>(catv4, cath4, tB >> 5, gl, fB);
            const float4* wrA = &sW4[(tA & 31) * WSTRIDE + gl * 2];
            const float4* wrB = &sW4[(tB & 31) * WSTRIDE + gl * 2];
            float4 wa0 = wrA[0], wa1 = wrA[1];
            float4 wb0 = wrB[0], wb1 = wrB[1];
            FMA8(accA, wA, fA, wa0, wa1)
            FMA8(accB, wB, fB, wb0, wb1)
        }
    } else {
        float m = -FLT_MAX;
        for (int j = lane; j < deg; j += 64) {
            int rec = sorted_ta[start + j];
            int tt = rec >> 5, r = rec & 31;
            m = fmaxf(m, norm2[h * N_REL + r] * norm2[(size_t)tt * N_REL + r]);
        }
#pragma unroll
        for (int off = 32; off > 0; off >>= 1) m = fmaxf(m, __shfl_xor(m, off));
        float ssum = 0.f;
        for (int j = lane; j < deg; j += 64) {
            int rec = sorted_ta[start + j];
            int tt = rec >> 5, r = rec & 31;
            ssum += __expf(norm2[h * N_REL + r] * norm2[(size_t)tt * N_REL + r] - m);
        }
#pragma unroll
        for (int off = 32; off > 0; off >>= 1) ssum += __shfl_xor(ssum, off);
        float inv = 1.f / ssum;
        for (int j0 = 0; j0 < deg; j0 += 64) {
            int n = min(64, deg - j0);
            int   rec = 0;
            float w   = 0.f;
            if (lane < n) {
                rec = sorted_ta[start + j0 + lane];
                int tt = rec >> 5, r = rec & 31;
                w = __expf(norm2[h * N_REL + r] * norm2[(size_t)tt * N_REL + r] - m) * inv;
            }
            for (int e = 0; e < n; e += 16) {
                int   tA = __shfl(rec, e + grp);
                float wA = __shfl(w,   e + grp);
                int   tB = __shfl(rec, e + 8 + grp);
                float wB = __shfl(w,   e + 8 + grp);
                float fA[8], fB[8];
                load_row8<F16>(catv4, cath4, tA >> 5, gl, fA);
                load_row8<F16>(catv4, cath4, tB >> 5, gl, fB);
                const float4* wrA = &sW4[(tA & 31) * WSTRIDE + gl * 2];
                const float4* wrB = &sW4[(tB & 31) * WSTRIDE + gl * 2];
                float4 wa0 = wrA[0], wa1 = wrA[1];
                float4 wb0 = wrB[0], wb1 = wrB[1];
                FMA8(accA, wA, fA, wa0, wa1)
                FMA8(accB, wB, fB, wb0, wb1)
            }
        }
    }

    float a[8];
#pragma unroll
    for (int k = 0; k < 8; ++k) a[k] = accA[k] + accB[k];
    float tot = reduce_scatter8(a, lane);
    scr[wv][dim_of_lane(lane)] = tot;         // 2-way bank alias: free
    // wave-private exchange: in-wave LDS ops are ordered; no barrier needed
    if (lane < 16) {
        float4 o = ((const float4*)scr[wv])[lane];
        ((float4*)&cat_agg[(size_t)h * D])[lane] = o;
    }
}

// spmm: gather + reduce-scatter only; epilogue is one coalesced multiply by
// the precomputed scale (read from uagg in place). ~17 DS ops/wave.
template<int F16>
__global__ __launch_bounds__(256, 4) void spmm_user_kernel(
        const int* __restrict__ offs_u,
        const int2* __restrict__ sorted_cv,
        const float* __restrict__ cat,
        const uint4* __restrict__ cath4,
        float* __restrict__ uagg) {
    __shared__ float scr[4][D];               // 1 KB
    const float4* catv4 = (const float4*)cat;
    int wv   = threadIdx.x >> 6;
    int lane = threadIdx.x & 63;
    int grp  = lane >> 3;
    int gl   = lane & 7;
    int u = blockIdx.x * 4 + wv;
    int start = offs_u[u];
    int end   = offs_u[u + 1];
    int deg   = end - start;

    float accA[8], accB[8];
#pragma unroll
    for (int k = 0; k < 8; ++k) { accA[k] = 0.f; accB[k] = 0.f; }

    if (deg <= 32) {
        int my_c = 0; float my_v = 0.f;
        if (lane < deg) {
            int2 cv = sorted_cv[start + lane];
            my_c = cv.x;
            my_v = __int_as_float(cv.y);
        }
        int   cA0 = __shfl(my_c, grp),     cB0 = __shfl(my_c, 8 + grp);
        float vA0 = __shfl(my_v, grp),     vB0 = __shfl(my_v, 8 + grp);
        float fA0[8], fB0[8], fA1[8], fB1[8];
        load_row8<F16>(catv4, cath4, cA0, gl, fA0);
        load_row8<F16>(catv4, cath4, cB0, gl, fB0);
        float vA1 = 0.f, vB1 = 0.f;
        if (deg > 16) {
            int cA1 = __shfl(my_c, 16 + grp), cB1 = __shfl(my_c, 24 + grp);
            vA1 = __shfl(my_v, 16 + grp); vB1 = __shfl(my_v, 24 + grp);
            load_row8<F16>(catv4, cath4, cA1, gl, fA1);
            load_row8<F16>(catv4, cath4, cB1, gl, fB1);
#pragma unroll
            for (int k = 0; k < 8; ++k) {
                accA[k] += vA1 * fA1[k];
                accB[k] += vB1 * fB1[k];
            }
        }
#pragma unroll
        for (int k = 0; k < 8; ++k) {
            accA[k] += vA0 * fA0[k];
            accB[k] += vB0 * fB0[k];
        }
    } else {
        for (int j0 = 0; j0 < deg; j0 += 64) {
            int n = min(64, deg - j0);
            int   my_c = 0;
            float my_v = 0.f;
            if (lane < n) {
                int2 cv = sorted_cv[start + j0 + lane];
                my_c = cv.x;
                my_v = __int_as_float(cv.y);
            }
            for (int e = 0; e < n; e += 16) {
                int   cA = __shfl(my_c, e + grp);
                float vA = __shfl(my_v, e + grp);
                int   cB = __shfl(my_c, e + 8 + grp);
                float vB = __shfl(my_v, e + 8 + grp);
                float fA[8], fB[8];
                load_row8<F16>(catv4, cath4, cA, gl, fA);
                load_row8<F16>(catv4, cath4, cB, gl, fB);
#pragma unroll
                for (int k = 0; k < 8; ++k) {
                    accA[k] += vA * fA[k];
                    accB[k] += vB * fB[k];
                }
            }
        }
    }

    float a[8];
#pragma unroll
    for (int k = 0; k < 8; ++k) a[k] = accA[k] + accB[k];
    float tot = reduce_scatter8(a, lane);
    scr[wv][dim_of_lane(lane)] = tot;
    if (lane < 16) {
        float4 o = ((const float4*)scr[wv])[lane];
        float4* row = (float4*)&uagg[(size_t)u * D];
        float4 s = row[lane];                 // scale = 1 + proj (precomputed)
        row[lane] = make_float4(o.x * s.x, o.y * s.y, o.z * s.z, o.w * s.w);
    }
}

extern "C" void kernel_launch(void* const* d_in, const int* in_sizes, int n_in,
                              void* d_out, int out_size, void* d_ws, size_t ws_size,
                              hipStream_t stream) {
    const float* cat   = (const float*)d_in[0];
    const float* uemb  = (const float*)d_in[1];
    const int*   eidx  = (const int*)d_in[2];
    const int*   etype = (const int*)d_in[3];
    const int*   imr   = (const int*)d_in[4];
    const int*   imc   = (const int*)d_in[5];
    const float* imv   = (const float*)d_in[6];
    const float* W     = (const float*)d_in[7];
    const int* head = eidx;
    const int* tail = eidx + NEDGE;

    float* out     = (float*)d_out;
    float* cat_agg = out;                         // [N_CAT, D]
    float* uagg    = out + (size_t)N_CAT * D;     // [N_USERS, D]

    float* norm2   = (float*)d_ws;
    int*   ccnt    = (int*)(norm2 + (size_t)N_CAT * N_REL);
    int*   cbase_e = ccnt + NBK;
    int*   cbase_u = cbase_e + NBKE + 1;
    int*   ccur_e  = cbase_u + NBKU + 1;
    int*   ccur_u  = ccur_e + NBKE;
    int*   offs_e  = ccur_u + NBKU;
    int*   offs_u  = offs_e + N_CAT + 1;
    int*   sorted_ta = offs_u + N_USERS + 1;
    int2*  sorted_cv = (int2*)(sorted_ta + NEDGE);

    unsigned short* cath_us =
        (unsigned short*)(((uintptr_t)(sorted_cv + NNZ) + 255) & ~(uintptr_t)255);
    size_t need = (size_t)((char*)(cath_us + (size_t)N_CAT * D) - (char*)d_ws);
    int use16 = (ws_size >= need);

    hipMemsetAsync(ccnt, 0, (size_t)NBK * sizeof(int), stream);

    coarse_hist_kernel<<<512, 256, 0, stream>>>(head, imr, ccnt);
    coarse_scan_kernel<<<1, 256, 0, stream>>>(ccnt, cbase_e, cbase_u,
                                              ccur_e, ccur_u, offs_e, offs_u);
    pass1_edges_kernel<<<(NEDGE + T1 - 1) / T1, 256, 0, stream>>>(
        head, tail, etype, ccur_e, sorted_ta);
    pass1_users_kernel<<<(NNZ + T1 - 1) / T1, 256, 0, stream>>>(
        imr, imc, imv, ccur_u, sorted_cv);
    pass2_kernel<<<NBK, 256, 0, stream>>>(cbase_e, cbase_u, offs_e, offs_u,
                                          sorted_ta, sorted_cv);
    // scale = 1 + softmax(U W^T) W  -> uagg (consumed in place by spmm)
    scale_kernel<<<(N_USERS + 63) / 64, 256, 0, stream>>>(uemb, W, uagg);
    if (use16) {
        norm2_kernel<1><<<(N_CAT + 63) / 64, 256, 0, stream>>>(cat, W, norm2, cath_us);
        cat_agg_sorted_kernel<1><<<N_CAT / 4, 256, 0, stream>>>(
            offs_e, sorted_ta, norm2, cat, (const uint4*)cath_us, W, cat_agg);
        spmm_user_kernel<1><<<N_USERS / 4, 256, 0, stream>>>(
            offs_u, sorted_cv, cat, (const uint4*)cath_us, uagg);
    } else {
        norm2_kernel<0><<<(N_CAT + 63) / 64, 256, 0, stream>>>(cat, W, norm2, nullptr);
        cat_agg_sorted_kernel<0><<<N_CAT / 4, 256, 0, stream>>>(
            offs_e, sorted_ta, norm2, cat, nullptr, W, cat_agg);
        spmm_user_kernel<0><<<N_USERS / 4, 256, 0, stream>>>(
            offs_u, sorted_cv, cat, nullptr, uagg);
    }
}